// Round 13
// baseline (259.467 us; speedup 1.0000x reference)
//
#include <hip/hip_runtime.h>
#include <hip/hip_bf16.h>

typedef unsigned int u32;
typedef unsigned long long u64;
typedef unsigned short u16;
typedef float f32x4 __attribute__((ext_vector_type(4)));
typedef float f32x16 __attribute__((ext_vector_type(16)));
typedef short bh8 __attribute__((ext_vector_type(8)));   // 8 bf16 operand frag

#define NB 16
#define NN 128
#define DD 128

__device__ __forceinline__ u16 f2bf(float f) {
  union { float f; u32 u; } x; x.f = f;
  u32 r = (x.u + 0x7fffu + ((x.u >> 16) & 1u)) >> 16;
  return (u16)r;
}
__device__ __forceinline__ u32 cvtpk(float lo, float hi) {
  u32 r;
  asm("v_cvt_pk_bf16_f32 %0, %1, %2" : "=v"(r) : "v"(lo), "v"(hi));
  return r;
}
__device__ __forceinline__ float bf2f(u16 h) {
  union { u32 u; float f; } x; x.u = ((u32)h) << 16;
  return x.f;
}
__device__ __forceinline__ float lrelu(float x) { return fmaxf(x, 0.01f * x); }
__device__ __forceinline__ f32x16 zero16() {
  f32x16 v;
  #pragma unroll
  for (int r = 0; r < 16; ++r) v[r] = 0.f;
  return v;
}

// ---------------- unified weight pack/convert ----------------
__global__ void k_pack(const float* __restrict__ ps_w1, const float* __restrict__ ps_w2,
                       const float* __restrict__ d2p_w1, const float* __restrict__ d2p_w2,
                       const float* __restrict__ wq, const float* __restrict__ wk,
                       u16* __restrict__ w1p, u16* __restrict__ w2p,
                       u16* __restrict__ wqA, u16* __restrict__ wkA,
                       u16* __restrict__ w1A, u16* __restrict__ w2A)
{
  int idx = blockIdx.x * 256 + threadIdx.x;
  if (idx < 65536) {
    int r = idx & 7, lane = (idx >> 3) & 63, f = (idx >> 9) & 63, g = idx >> 15;
    int ct = f >> 3, ks = f & 7;
    int c = ct * 32 + (lane & 31), d = ks * 16 + (lane >> 5) * 8 + r;
    w1p[idx] = f2bf(ps_w1[(size_t)g * 32768 + c * 128 + d]);
    return;
  }
  idx -= 65536;
  if (idx < 65536) {
    int r = idx & 7, lane = (idx >> 3) & 63, f = (idx >> 9) & 63, g = idx >> 15;
    int et = f >> 4, ks2 = f & 15;
    int e = et * 32 + (lane & 31), c = ks2 * 16 + (lane >> 5) * 8 + r;
    w2p[idx] = f2bf(ps_w2[(size_t)g * 32768 + e * 256 + c]);
    return;
  }
  idx -= 65536;
  if (idx < 32768) {
    int r = idx & 7, lane = (idx >> 3) & 63, ks = (idx >> 9) & 7, ot = (idx >> 12) & 3, g = idx >> 14;
    int o = ot * 32 + (lane & 31), d = ks * 16 + (lane >> 5) * 8 + r;
    wqA[idx] = f2bf(wq[(size_t)g * 16384 + o * 128 + d]);
    return;
  }
  idx -= 32768;
  if (idx < 32768) {
    int r = idx & 7, lane = (idx >> 3) & 63, ks = (idx >> 9) & 7, ot = (idx >> 12) & 3, g = idx >> 14;
    int o = ot * 32 + (lane & 31), d = ks * 16 + (lane >> 5) * 8 + r;
    wkA[idx] = f2bf(wk[(size_t)g * 16384 + o * 128 + d]);
    return;
  }
  idx -= 32768;
  if (idx < 131072) {
    int r = idx & 7, lane = (idx >> 3) & 63, ks = (idx >> 9) & 15, ot = (idx >> 13) & 7, g = idx >> 16;
    int o = ot * 32 + (lane & 31), q = ks * 16 + (lane >> 5) * 8 + r;
    w1A[idx] = f2bf(d2p_w1[(size_t)g * 65536 + o * 256 + q]);
    return;
  }
  idx -= 131072;
  if (idx < 65536) {
    int r = idx & 7, lane = (idx >> 3) & 63, ks = (idx >> 9) & 15, ot = (idx >> 13) & 3, g = idx >> 15;
    int o = ot * 32 + (lane & 31), q = ks * 16 + (lane >> 5) * 8 + r;
    w2A[idx] = f2bf(d2p_w2[(size_t)g * 32768 + o * 256 + q]);
    return;
  }
}

// ---------------- point-sim: a1-resident, a2 per-use from L2; 3 blocks/CU ----------------
__global__ __launch_bounds__(256, 3)
void k_point_sim(const float* __restrict__ vp,
                 const u16* __restrict__ w1p, const u16* __restrict__ w2p,
                 const float* __restrict__ g1v, const float* __restrict__ b1v,
                 const float* __restrict__ g2v, const float* __restrict__ b2v,
                 const float* __restrict__ w3v, const float* __restrict__ b3v,
                 float* __restrict__ s_out, float* __restrict__ sims_out)
{
  // bijective XCD swizzle (1152 % 8 == 0, q = 144)
  const int orig = blockIdx.x;
  const int bid = (orig & 7) * 144 + (orig >> 3);
  const int half = bid & 1;
  int rem = (bid >> 1) % 36;
  const int b = (bid >> 1) / 36;
  int ti = 0;
  while (rem >= 8 - ti) { rem -= 8 - ti; ++ti; }
  const int tj = ti + rem;

  const int t = threadIdx.x;
  const int lane = t & 63;
  const int w = t >> 6;
  const int p_l = lane & 31;
  const int hi = lane >> 5;
  const float rsbn = rsqrtf(1.0f + 1e-5f);

  __shared__ u16 Adiff[2][32 * 128];     // 16 KB
  __shared__ u16 HL[2][32 * 256];        // 32 KB
  __shared__ float sc1[256], bb1[256];   // 2 KB
  __shared__ float sc2[128], bb2[128], w3s[128];  // 1.5 KB
  __shared__ float sred[2][4][32];       // 1 KB -> total 53760 B -> 3 blocks/CU

  sc1[t] = g1v[t] * rsbn; bb1[t] = b1v[t];
  if (t < 128) { sc2[t] = g2v[t] * rsbn; bb2[t] = b2v[t]; w3s[t] = w3v[t]; }

  bh8 a1[2][8];
  #pragma unroll
  for (int c2 = 0; c2 < 2; ++c2)
    #pragma unroll
    for (int ks = 0; ks < 8; ++ks)
      a1[c2][ks] = *(const bh8*)(w1p + (((w * 2 + c2) * 8 + ks) * 64 + lane) * 8);

  const int mtA = half * 4;
  const float* vpb = vp + (size_t)b * NN * DD;

  auto diffgen = [&](int mt, int buf) {
    int p = t >> 3, dseg = t & 7;
    int il = mt * 2 + (p >> 4), jl = p & 15;
    int i = ti * 16 + il, j = tj * 16 + jl;
    const float4* vi = (const float4*)(vpb + i * DD + dseg * 16);
    const float4* vj = (const float4*)(vpb + j * DD + dseg * 16);
    float rs = 0.f;
    u32 pw[8];
    #pragma unroll
    for (int c = 0; c < 4; ++c) {
      float4 av = vi[c], bv = vj[c];
      float d0 = av.x - bv.x; d0 *= d0;
      float d1 = av.y - bv.y; d1 *= d1;
      float d2 = av.z - bv.z; d2 *= d2;
      float d3 = av.w - bv.w; d3 *= d3;
      rs += d0 + d1 + d2 + d3;
      pw[c * 2]     = cvtpk(d0, d1);
      pw[c * 2 + 1] = cvtpk(d2, d3);
    }
    int base = p * 256;
    int off0 = (dseg * 32) ^ ((p & 15) << 4);
    int off1 = (dseg * 32 + 16) ^ ((p & 15) << 4);
    uint4 q0; q0.x = pw[0]; q0.y = pw[1]; q0.z = pw[2]; q0.w = pw[3];
    uint4 q1; q1.x = pw[4]; q1.y = pw[5]; q1.z = pw[6]; q1.w = pw[7];
    *(uint4*)((char*)Adiff[buf] + base + off0) = q0;
    *(uint4*)((char*)Adiff[buf] + base + off1) = q1;
    rs += __shfl_xor(rs, 1);
    rs += __shfl_xor(rs, 2);
    rs += __shfl_xor(rs, 4);
    if ((t & 7) == 0) {
      sims_out[(size_t)(b * NN + i) * NN + j] = -rs;
      if (ti != tj) sims_out[(size_t)(b * NN + j) * NN + i] = -rs;
    }
  };

  auto do_l2 = [&](int src) {
    f32x16 acc2 = zero16();
    __builtin_amdgcn_s_setprio(1);
    #pragma unroll
    for (int ks2 = 0; ks2 < 16; ++ks2) {
      int byte = p_l * 512 + ((ks2 * 32 + hi * 16) ^ (p_l << 4));
      bh8 bf = *(const bh8*)((const char*)HL[src] + byte);
      // W2 fragment loaded per-use; volatile u64 pair defeats LICM hoisting
      const volatile u64* wp = (const volatile u64*)(w2p + ((w * 16 + ks2) * 64 + lane) * 8);
      u64 lo = wp[0], hi2 = wp[1];
      u32 arr[4] = { (u32)lo, (u32)(lo >> 32), (u32)hi2, (u32)(hi2 >> 32) };
      bh8 a2v = *(bh8*)arr;
      acc2 = __builtin_amdgcn_mfma_f32_32x32x16_bf16(a2v, bf, acc2, 0, 0, 0);
    }
    __builtin_amdgcn_s_setprio(0);
    float psum = 0.f;
    #pragma unroll
    for (int r = 0; r < 16; ++r) {
      int e = w * 32 + (r & 3) + 8 * (r >> 2) + 4 * hi;
      float v = lrelu(acc2[r] * sc2[e] + bb2[e]);
      psum += v * w3s[e];
    }
    psum += __shfl_xor(psum, 32);
    if (hi == 0) sred[src][w][p_l] = psum;
  };

  auto s_final = [&](int ml) {
    if (t < 32) {
      float z = sred[ml & 1][0][t] + sred[ml & 1][1][t] + sred[ml & 1][2][t]
              + sred[ml & 1][3][t] + b3v[0];
      float sv = 1.f / (1.f + __expf(-z));
      int i = ti * 16 + (mtA + ml) * 2 + (t >> 4);
      int j = tj * 16 + (t & 15);
      s_out[(size_t)(b * NN + i) * NN + j] = sv;
      if (ti != tj) s_out[(size_t)(b * NN + j) * NN + i] = sv;
    }
  };

  diffgen(mtA, 0);
  __syncthreads();

  #pragma unroll
  for (int m = 0; m < 4; ++m) {
    const int cur = m & 1;
    f32x16 acc1[2];
    acc1[0] = zero16(); acc1[1] = zero16();
    __builtin_amdgcn_s_setprio(1);
    #pragma unroll
    for (int ks = 0; ks < 8; ++ks) {
      int byte = p_l * 256 + ((ks * 32 + hi * 16) ^ ((p_l & 15) << 4));
      bh8 bf = *(const bh8*)((const char*)Adiff[cur] + byte);
      acc1[0] = __builtin_amdgcn_mfma_f32_32x32x16_bf16(a1[0][ks], bf, acc1[0], 0, 0, 0);
      acc1[1] = __builtin_amdgcn_mfma_f32_32x32x16_bf16(a1[1][ks], bf, acc1[1], 0, 0, 0);
    }
    __builtin_amdgcn_s_setprio(0);
    if (m < 3) diffgen(mtA + m + 1, cur ^ 1);
    if (m > 0) do_l2(cur ^ 1);
    if (m >= 2) s_final(m - 2);
    #pragma unroll
    for (int c2 = 0; c2 < 2; ++c2) {
      #pragma unroll
      for (int g4 = 0; g4 < 4; ++g4) {
        int c0 = (w * 2 + c2) * 32 + g4 * 8 + hi * 4;
        float v0 = lrelu(acc1[c2][g4 * 4 + 0] * sc1[c0 + 0] + bb1[c0 + 0]);
        float v1 = lrelu(acc1[c2][g4 * 4 + 1] * sc1[c0 + 1] + bb1[c0 + 1]);
        float v2 = lrelu(acc1[c2][g4 * 4 + 2] * sc1[c0 + 2] + bb1[c0 + 2]);
        float v3 = lrelu(acc1[c2][g4 * 4 + 3] * sc1[c0 + 3] + bb1[c0 + 3]);
        uint2 pk;
        pk.x = cvtpk(v0, v1);
        pk.y = cvtpk(v2, v3);
        int byte = p_l * 512 + ((c0 * 2) ^ (p_l << 4));
        *(uint2*)((char*)HL[cur] + byte) = pk;
      }
    }
    __syncthreads();
  }
  do_l2(1);
  s_final(2);
  __syncthreads();
  s_final(3);
}

// ---------------- top-k rank scatter ----------------
__global__ void k_rank(const float* __restrict__ s_buf, const float* __restrict__ ep_prev,
                       float* __restrict__ mask)
{
  const int b = blockIdx.x >> 7, n = blockIdx.x & 127, t = threadIdx.x;
  __shared__ float ev[NN];
  size_t row = (size_t)(b * NN + n) * NN;
  float v = s_buf[row + t] * ((t == n) ? 0.f : ep_prev[row + t]);
  ev[t] = v;
  __syncthreads();
  int r = 0;
  for (int j = 0; j < NN; ++j) {
    float vj = ev[j];
    r += (vj > v) || (vj == v && j < t);
  }
  if (r < 115) mask[(size_t)(b * NN + t) * NN + r] = 1.0f;
}

// ---------------- fused: edge normalization + prep ----------------
__global__ __launch_bounds__(256)
void k_edge_prep(const float* __restrict__ s_buf, const float* __restrict__ ep_prev,
                 float* __restrict__ maskb, int use_mask, float* __restrict__ eps_out,
                 const float* __restrict__ vp,
                 const u16* __restrict__ wqA, const u16* __restrict__ wkA,
                 u16* __restrict__ Qb, u16* __restrict__ Kb,
                 u16* __restrict__ VPb, u16* __restrict__ VPT)
{
  __shared__ char shm[8448];
  const int t = threadIdx.x;

  if (blockIdx.x < 1024) {
    float* red  = (float*)shm;        // [2][2][2]
    float* red2 = (float*)shm + 8;    // [2][2]
    const int rr = t >> 7, tl = t & 127;
    const int rowid = blockIdx.x * 2 + rr;
    const int i = rowid & 127;
    const int wl = (t >> 6) & 1;
    size_t row = (size_t)rowid * 128;
    float ep0 = (tl == i) ? 0.f : ep_prev[row + tl];
    float e = s_buf[row + tl] * ep0;
    if (use_mask) e *= maskb[row + tl];
    else maskb[row + tl] = 0.f;
    float a = ep0, c = fabsf(e);
    #pragma unroll
    for (int o = 32; o; o >>= 1) { a += __shfl_xor(a, o); c += __shfl_xor(c, o); }
    if ((t & 63) == 0) { red[(rr * 2 + wl) * 2 + 0] = a; red[(rr * 2 + wl) * 2 + 1] = c; }
    __syncthreads();
    float epsum = red[(rr * 2) * 2] + red[(rr * 2 + 1) * 2];
    float l1 = red[(rr * 2) * 2 + 1] + red[(rr * 2 + 1) * 2 + 1];
    e = e / fmaxf(l1, 1e-12f) * epsum;
    e += ((tl == i) ? 1.f : 0.f) + 1e-6f;
    float d = e;
    #pragma unroll
    for (int o = 32; o; o >>= 1) d += __shfl_xor(d, o);
    if ((t & 63) == 0) red2[rr * 2 + wl] = d;
    __syncthreads();
    eps_out[row + tl] = e / (red2[rr * 2] + red2[rr * 2 + 1]);
    return;
  }

  u16* VPs = (u16*)shm;   // [32][128] bf16 swizzled (8 KB)
  const int pb = blockIdx.x - 1024;
  const int b = pb >> 2, nt = pb & 3;
  const int w = t >> 6, lane = t & 63, l31 = lane & 31, hi = lane >> 5;
  const float* vpb = vp + (size_t)b * 16384 + (size_t)nt * 32 * 128;

  {
    int r = t >> 3, cseg = t & 7;
    float v[16];
    const float4* src = (const float4*)(vpb + r * 128 + cseg * 16);
    #pragma unroll
    for (int c = 0; c < 4; ++c) {
      float4 a = src[c];
      v[c * 4 + 0] = a.x; v[c * 4 + 1] = a.y; v[c * 4 + 2] = a.z; v[c * 4 + 3] = a.w;
    }
    uint4 pk0, pk1;
    u32* p0 = (u32*)&pk0; u32* p1 = (u32*)&pk1;
    #pragma unroll
    for (int k = 0; k < 4; ++k) {
      p0[k] = cvtpk(v[k * 2 + 0], v[k * 2 + 1]);
      p1[k] = cvtpk(v[8 + k * 2 + 0], v[8 + k * 2 + 1]);
    }
    u16* vb = VPb + (size_t)b * 16384 + (nt * 32 + r) * 128 + cseg * 16;
    *(uint4*)(vb) = pk0;
    *(uint4*)(vb + 8) = pk1;
    *(uint4*)((char*)VPs + r * 256 + ((cseg * 32) ^ ((r & 15) << 4))) = pk0;
    *(uint4*)((char*)VPs + r * 256 + ((cseg * 32 + 16) ^ ((r & 15) << 4))) = pk1;
  }
  __syncthreads();

  {
    int col = t >> 1, hh = t & 1;
    u16 tmp[16];
    #pragma unroll
    for (int rr2 = 0; rr2 < 16; ++rr2) {
      int row = hh * 16 + rr2;
      tmp[rr2] = *(const u16*)((char*)VPs + row * 256 + ((col * 2) ^ ((row & 15) << 4)));
    }
    *(uint4*)(VPT + (size_t)b * 16384 + col * 128 + nt * 32 + hh * 16) = *(uint4*)&tmp[0];
    *(uint4*)(VPT + (size_t)b * 16384 + col * 128 + nt * 32 + hh * 16 + 8) = *(uint4*)&tmp[8];
  }

  {
    const int isK = w >> 1;
    const int otp = (w & 1) * 2;
    const u16* wA = isK ? wkA : wqA;
    u16* DST = (isK ? Kb : Qb) + (size_t)b * 16384;
    bh8 bf[8];
    #pragma unroll
    for (int ks = 0; ks < 8; ++ks)
      bf[ks] = *(const bh8*)((char*)VPs + l31 * 256 + (((ks * 32) + hi * 16) ^ ((l31 & 15) << 4)));
    #pragma unroll
    for (int oo = 0; oo < 2; ++oo) {
      int ot = otp + oo;
      f32x16 acc = zero16();
      #pragma unroll
      for (int ks = 0; ks < 8; ++ks) {
        bh8 af = *(const bh8*)(wA + ((size_t)(ot * 8 + ks) * 64 + lane) * 8);
        acc = __builtin_amdgcn_mfma_f32_32x32x16_bf16(af, bf[ks], acc, 0, 0, 0);
      }
      int n = nt * 32 + l31;
      #pragma unroll
      for (int q4 = 0; q4 < 4; ++q4) {
        int o0 = ot * 32 + q4 * 8 + hi * 4;
        uint2 pk;
        pk.x = cvtpk(acc[q4 * 4 + 0], acc[q4 * 4 + 1]);
        pk.y = cvtpk(acc[q4 * 4 + 2], acc[q4 * 4 + 3]);
        *(uint2*)(DST + n * 128 + o0) = pk;
      }
    }
  }
}

// ---------------- fused attn + fuse + l1 + aggr + MLP1 + MLP2 ----------------
__global__ __launch_bounds__(256)
void k_attn_d2p(const u16* __restrict__ Qb, const u16* __restrict__ Kb,
                const float* __restrict__ eps_g,
                const u16* __restrict__ VPb, const u16* __restrict__ VPT,
                const u16* __restrict__ w1A, const float* __restrict__ g1v, const float* __restrict__ b1v,
                const u16* __restrict__ w2A, const float* __restrict__ g2v, const float* __restrict__ b2v,
                float* __restrict__ vpn)
{
  __shared__ char shm[40960];
  u16* att  = (u16*)shm;             // 32 KB (dead after phase B)
  u16* AG   = (u16*)shm;             // 8 KB  aggr
  u16* HB   = (u16*)(shm + 8192);    // 16 KB h1
  u16* EFNl = (u16*)(shm + 32768);   // 8 KB

  const int b = blockIdx.x >> 2;
  const int ch = blockIdx.x & 3;
  const int t = threadIdx.x;
  const int w = t >> 6;
  const int lane = t & 63;
  const int l31 = lane & 31;
  const int hi = lane >> 5;
  const float rsbn = rsqrtf(1.f + 1e-5f);

  // ---- A: per-head logits + in-lane softmax + 2-head partial sum ----
  {
    float asum[64];
    #pragma unroll
    for (int z = 0; z < 64; ++z) asum[z] = 0.f;
    const u16* Qrow = Qb + (size_t)b * 16384 + (ch * 32 + l31) * 128;
    #pragma unroll
    for (int hh = 0; hh < 2; ++hh) {
      int h = w * 2 + hh;
      bh8 qf = *(const bh8*)(Qrow + h * 16 + hi * 8);
      f32x16 lg[4];
      #pragma unroll
      for (int jt = 0; jt < 4; ++jt) {
        bh8 kf = *(const bh8*)(Kb + (size_t)b * 16384 + (jt * 32 + l31) * 128 + h * 16 + hi * 8);
        f32x16 zz = zero16();
        lg[jt] = __builtin_amdgcn_mfma_f32_32x32x16_bf16(kf, qf, zz, 0, 0, 0);
      }
      float m = lg[0][0];
      #pragma unroll
      for (int jt = 0; jt < 4; ++jt)
        #pragma unroll
        for (int r = 0; r < 16; ++r) m = fmaxf(m, lg[jt][r]);
      m = fmaxf(m, __shfl_xor(m, 32));
      float sum = 0.f;
      #pragma unroll
      for (int jt = 0; jt < 4; ++jt)
        #pragma unroll
        for (int r = 0; r < 16; ++r) {
          float e = __expf((lg[jt][r] - m) * 0.25f);
          lg[jt][r] = e;
          sum += e;
        }
      sum += __shfl_xor(sum, 32);
      float inv = 1.f / sum;
      #pragma unroll
      for (int jt = 0; jt < 4; ++jt)
        #pragma unroll
        for (int r = 0; r < 16; ++r) asum[jt * 16 + r] += lg[jt][r] * inv;
    }
    #pragma unroll
    for (int jt = 0; jt < 4; ++jt)
      #pragma unroll
      for (int q4 = 0; q4 < 4; ++q4) {
        int j0 = jt * 32 + q4 * 8 + hi * 4;
        uint2 pk;
        pk.x = cvtpk(asum[jt * 16 + q4 * 4 + 0], asum[jt * 16 + q4 * 4 + 1]);
        pk.y = cvtpk(asum[jt * 16 + q4 * 4 + 2], asum[jt * 16 + q4 * 4 + 3]);
        *(uint2*)((char*)att + (w * 32 + l31) * 256 + ((j0 * 2) ^ ((l31 & 15) << 4))) = pk;
      }
  }
  __syncthreads();

  // ---- B: combine partials, fuse with eps, l1-normalize -> EFNl ----
  {
    int il = t >> 3, jseg = t & 7;
    int i = ch * 32 + il;
    float a[16];
    #pragma unroll
    for (int z = 0; z < 16; ++z) a[z] = 0.f;
    #pragma unroll
    for (int ww = 0; ww < 4; ++ww) {
      #pragma unroll
      for (int c = 0; c < 2; ++c) {
        uint4 v = *(const uint4*)((char*)att + (ww * 32 + il) * 256 + (((jseg * 32) + c * 16) ^ ((il & 15) << 4)));
        u32 uu[4] = {v.x, v.y, v.z, v.w};
        #pragma unroll
        for (int k = 0; k < 4; ++k) {
          a[c * 8 + k * 2 + 0] += bf2f((u16)(uu[k] & 0xffff));
          a[c * 8 + k * 2 + 1] += bf2f((u16)(uu[k] >> 16));
        }
      }
    }
    const float* erow = eps_g + ((size_t)b * 128 + i) * 128 + jseg * 16;
    float f[16];
    float s = 0.f;
    #pragma unroll
    for (int c = 0; c < 4; ++c) {
      float4 ev = *(const float4*)(erow + c * 4);
      float evs[4] = {ev.x, ev.y, ev.z, ev.w};
      #pragma unroll
      for (int k = 0; k < 4; ++k) {
        int jj = jseg * 16 + c * 4 + k;
        float fv = 0.5f * (evs[k] + a[c * 4 + k] * 0.125f);
        if (jj == i) fv = 0.f;
        f[c * 4 + k] = fv;
        s += fabsf(fv);
      }
    }
    s += __shfl_xor(s, 1);
    s += __shfl_xor(s, 2);
    s += __shfl_xor(s, 4);
    float inv = 1.f / fmaxf(s, 1e-12f);
    uint4 o0, o1;
    u32* op = (u32*)&o0;
    u32* op1 = (u32*)&o1;
    #pragma unroll
    for (int k = 0; k < 4; ++k) {
      op[k]  = cvtpk(f[k * 2 + 0] * inv, f[k * 2 + 1] * inv);
      op1[k] = cvtpk(f[8 + k * 2 + 0] * inv, f[8 + k * 2 + 1] * inv);
    }
    __syncthreads();
    *(uint4*)((char*)EFNl + il * 256 + ((jseg * 32) ^ ((il & 15) << 4))) = o0;
    *(uint4*)((char*)EFNl + il * 256 + ((jseg * 32 + 16) ^ ((il & 15) << 4))) = o1;
  }
  __syncthreads();

  // ---- C: aggr C[d][i] = sum_j vpT[d][j] * efn[i][j] ----
  {
    const u16* vtrow = VPT + (size_t)b * 16384 + (w * 32 + l31) * 128;
    f32x16 acc = zero16();
    #pragma unroll
    for (int ks = 0; ks < 8; ++ks) {
      bh8 af = *(const bh8*)(vtrow + ks * 16 + hi * 8);
      bh8 bf = *(const bh8*)((char*)EFNl + l31 * 256 + (((ks * 32) + hi * 16) ^ ((l31 & 15) << 4)));
      acc = __builtin_amdgcn_mfma_f32_32x32x16_bf16(af, bf, acc, 0, 0, 0);
    }
    #pragma unroll
    for (int q4 = 0; q4 < 4; ++q4) {
      int d0 = w * 32 + q4 * 8 + hi * 4;
      uint2 pk;
      pk.x = cvtpk(acc[q4 * 4 + 0], acc[q4 * 4 + 1]);
      pk.y = cvtpk(acc[q4 * 4 + 2], acc[q4 * 4 + 3]);
      *(uint2*)((char*)AG + l31 * 256 + ((d0 * 2) ^ ((l31 & 15) << 4))) = pk;
    }
  }
  __syncthreads();

  // ---- D: MLP1 ----
  {
    const u16* vprow = VPb + (size_t)b * 16384 + (ch * 32 + l31) * 128;
    f32x16 acc0 = zero16(), acc1v = zero16();
    #pragma unroll
    for (int ks = 0; ks < 16; ++ks) {
      bh8 a0 = *(const bh8*)(w1A + ((size_t)((w * 2 + 0) * 16 + ks)) * 512 + lane * 8);
      bh8 a1 = *(const bh8*)(w1A + ((size_t)((w * 2 + 1) * 16 + ks)) * 512 + lane * 8);
      bh8 bf;
      if (ks < 8) bf = *(const bh8*)(vprow + ks * 16 + hi * 8);
      else bf = *(const bh8*)((char*)AG + l31 * 256 + ((((ks - 8) * 32) + hi * 16) ^ ((l31 & 15) << 4)));
      acc0 = __builtin_amdgcn_mfma_f32_32x32x16_bf16(a0, bf, acc0, 0, 0, 0);
      acc1v = __builtin_amdgcn_mfma_f32_32x32x16_bf16(a1, bf, acc1v, 0, 0, 0);
    }
    #pragma unroll
    for (int oo = 0; oo < 2; ++oo) {
      const f32x16& acc = oo ? acc1v : acc0;
      #pragma unroll
      for (int q4 = 0; q4 < 4; ++q4) {
        int o0 = (w * 2 + oo) * 32 + q4 * 8 + hi * 4;
        float4 gg = *(const float4*)(g1v + o0);
        float4 bb = *(const float4*)(b1v + o0);
        float v0 = lrelu(acc[q4 * 4 + 0] * (gg.x * rsbn) + bb.x);
        float v1 = lrelu(acc[q4 * 4 + 1] * (gg.y * rsbn) + bb.y);
        float v2 = lrelu(acc[q4 * 4 + 2] * (gg.z * rsbn) + bb.z);
        float v3 = lrelu(acc[q4 * 4 + 3] * (gg.w * rsbn) + bb.w);
        uint2 pk;
        pk.x = cvtpk(v0, v1);
        pk.y = cvtpk(v2, v3);
        *(uint2*)((char*)HB + l31 * 512 + ((o0 * 2) ^ (l31 << 4))) = pk;
      }
    }
  }
  __syncthreads();

  // ---- E: MLP2 -> vpn ----
  {
    f32x16 acc = zero16();
    #pragma unroll
    for (int ks = 0; ks < 16; ++ks) {
      bh8 af = *(const bh8*)(w2A + ((size_t)(w * 16 + ks)) * 512 + lane * 8);
      bh8 bf = *(const bh8*)((char*)HB + l31 * 512 + (((ks * 32) + hi * 16) ^ (l31 << 4)));
      acc = __builtin_amdgcn_mfma_f32_32x32x16_bf16(af, bf, acc, 0, 0, 0);
    }
    int i = ch * 32 + l31;
    #pragma unroll
    for (int q4 = 0; q4 < 4; ++q4) {
      int o0 = w * 32 + q4 * 8 + hi * 4;
      float4 gg = *(const float4*)(g2v + o0);
      float4 bb = *(const float4*)(b2v + o0);
      float4 ov;
      ov.x = lrelu(acc[q4 * 4 + 0] * (gg.x * rsbn) + bb.x);
      ov.y = lrelu(acc[q4 * 4 + 1] * (gg.y * rsbn) + bb.y);
      ov.z = lrelu(acc[q4 * 4 + 2] * (gg.z * rsbn) + bb.z);
      ov.w = lrelu(acc[q4 * 4 + 3] * (gg.w * rsbn) + bb.w);
      *(float4*)(vpn + ((size_t)b * 128 + i) * 128 + o0) = ov;
    }
  }
}

extern "C" void kernel_launch(void* const* d_in, const int* in_sizes, int n_in,
                              void* d_out, int out_size, void* d_ws, size_t ws_size,
                              hipStream_t stream)
{
  (void)in_sizes; (void)n_in; (void)out_size; (void)ws_size;
  const float* vp_in  = (const float*)d_in[0];
  const float* ep_in  = (const float*)d_in[1];
  const float* ps_w1  = (const float*)d_in[2];
  const float* ps_g1  = (const float*)d_in[3];
  const float* ps_b1  = (const float*)d_in[4];
  const float* ps_w2  = (const float*)d_in[5];
  const float* ps_g2  = (const float*)d_in[6];
  const float* ps_b2  = (const float*)d_in[7];
  const float* ps_w3  = (const float*)d_in[8];
  const float* ps_b3  = (const float*)d_in[9];
  const float* d2p_w1 = (const float*)d_in[10];
  const float* d2p_g1 = (const float*)d_in[11];
  const float* d2p_b1 = (const float*)d_in[12];
  const float* d2p_w2 = (const float*)d_in[13];
  const float* d2p_g2 = (const float*)d_in[14];
  const float* d2p_b2 = (const float*)d_in[15];
  const float* wq     = (const float*)d_in[16];
  const float* wk     = (const float*)d_in[17];

  float* out = (float*)d_out;
  float* eps_base  = out;                 // [2][16][128][128]
  float* sims_base = out + 524288;        // [2][16][128][128]
  float* vp_out    = out + 1048576;       // [16][128][128]

  char* ws = (char*)d_ws;
  float* s_buf = (float*)(ws + ((size_t)0 << 20));
  float* maskb = (float*)(ws + ((size_t)1 << 20));
  float* vp1   = (float*)(ws + ((size_t)2 << 20));
  u16* Qb   = (u16*)(ws + ((size_t)3 << 20));
  u16* Kb   = (u16*)(ws + ((size_t)3 << 20) + 524288);
  u16* VPb  = (u16*)(ws + ((size_t)4 << 20));
  u16* VPT  = (u16*)(ws + ((size_t)4 << 20) + 524288);
  u16* w1p  = (u16*)(ws + ((size_t)5 << 20));
  u16* w2p  = w1p + 65536;
  u16* wqA  = w2p + 65536;      // [g][4][8][512]
  u16* wkA  = wqA + 32768;
  u16* w1A  = wkA + 32768;      // [g][8][16][512]
  u16* w2A  = w1A + 131072;     // [g][4][16][512]

  k_pack<<<dim3(1536), 256, 0, stream>>>(ps_w1, ps_w2, d2p_w1, d2p_w2, wq, wk,
                                         w1p, w2p, wqA, wkA, w1A, w2A);

  for (int g = 0; g < 2; ++g) {
    const float* vpc = g ? (const float*)vp1 : vp_in;
    float* vpn = g ? vp_out : vp1;
    float* eps_g  = eps_base + (size_t)g * 262144;
    float* sims_g = sims_base + (size_t)g * 262144;
    const float* epprev = g ? eps_base : ep_in;

    k_point_sim<<<dim3(1152), 256, 0, stream>>>(vpc,
        w1p + (size_t)g * 32768, w2p + (size_t)g * 32768,
        ps_g1 + g * 256, ps_b1 + g * 256,
        ps_g2 + g * 128, ps_b2 + g * 128,
        ps_w3 + g * 128, ps_b3 + g, s_buf, sims_g);
    if (g) k_rank<<<dim3(2048), 128, 0, stream>>>(s_buf, epprev, maskb);
    k_edge_prep<<<dim3(1088), 256, 0, stream>>>(s_buf, epprev, maskb, g, eps_g,
        vpc, wqA + (size_t)g * 16384, wkA + (size_t)g * 16384, Qb, Kb, VPb, VPT);
    k_attn_d2p<<<dim3(64), 256, 0, stream>>>(Qb, Kb, eps_g, VPb, VPT,
        w1A + (size_t)g * 65536, d2p_g1 + g * 256, d2p_b1 + g * 256,
        w2A + (size_t)g * 32768, d2p_g2 + g * 128, d2p_b2 + g * 128, vpn);
  }
}

// Round 14
// 116.619 us; speedup vs baseline: 2.2249x; 2.2249x over previous
//
#include <hip/hip_runtime.h>
#include <hip/hip_bf16.h>

typedef unsigned int u32;
typedef unsigned short u16;
typedef float f32x4 __attribute__((ext_vector_type(4)));
typedef float f32x16 __attribute__((ext_vector_type(16)));
typedef short bh8 __attribute__((ext_vector_type(8)));   // 8 bf16 operand frag

#define NB 16
#define NN 128
#define DD 128

__device__ __forceinline__ u16 f2bf(float f) {
  union { float f; u32 u; } x; x.f = f;
  u32 r = (x.u + 0x7fffu + ((x.u >> 16) & 1u)) >> 16;
  return (u16)r;
}
__device__ __forceinline__ u32 cvtpk(float lo, float hi) {
  u32 r;
  asm("v_cvt_pk_bf16_f32 %0, %1, %2" : "=v"(r) : "v"(lo), "v"(hi));
  return r;
}
__device__ __forceinline__ float bf2f(u16 h) {
  union { u32 u; float f; } x; x.u = ((u32)h) << 16;
  return x.f;
}
__device__ __forceinline__ float lrelu(float x) { return fmaxf(x, 0.01f * x); }
__device__ __forceinline__ f32x16 zero16() {
  f32x16 v;
  #pragma unroll
  for (int r = 0; r < 16; ++r) v[r] = 0.f;
  return v;
}

// ---------------- unified weight pack/convert ----------------
__global__ void k_pack(const float* __restrict__ ps_w1, const float* __restrict__ ps_w2,
                       const float* __restrict__ d2p_w1, const float* __restrict__ d2p_w2,
                       const float* __restrict__ wq, const float* __restrict__ wk,
                       u16* __restrict__ w1p, u16* __restrict__ w2p,
                       u16* __restrict__ wqA, u16* __restrict__ wkA,
                       u16* __restrict__ w1A, u16* __restrict__ w2A)
{
  int idx = blockIdx.x * 256 + threadIdx.x;
  if (idx < 65536) {
    int r = idx & 7, lane = (idx >> 3) & 63, f = (idx >> 9) & 63, g = idx >> 15;
    int ct = f >> 3, ks = f & 7;
    int c = ct * 32 + (lane & 31), d = ks * 16 + (lane >> 5) * 8 + r;
    w1p[idx] = f2bf(ps_w1[(size_t)g * 32768 + c * 128 + d]);
    return;
  }
  idx -= 65536;
  if (idx < 65536) {
    int r = idx & 7, lane = (idx >> 3) & 63, f = (idx >> 9) & 63, g = idx >> 15;
    int et = f >> 4, ks2 = f & 15;
    int e = et * 32 + (lane & 31), c = ks2 * 16 + (lane >> 5) * 8 + r;
    w2p[idx] = f2bf(ps_w2[(size_t)g * 32768 + e * 256 + c]);
    return;
  }
  idx -= 65536;
  if (idx < 32768) {
    int r = idx & 7, lane = (idx >> 3) & 63, ks = (idx >> 9) & 7, ot = (idx >> 12) & 3, g = idx >> 14;
    int o = ot * 32 + (lane & 31), d = ks * 16 + (lane >> 5) * 8 + r;
    wqA[idx] = f2bf(wq[(size_t)g * 16384 + o * 128 + d]);
    return;
  }
  idx -= 32768;
  if (idx < 32768) {
    int r = idx & 7, lane = (idx >> 3) & 63, ks = (idx >> 9) & 7, ot = (idx >> 12) & 3, g = idx >> 14;
    int o = ot * 32 + (lane & 31), d = ks * 16 + (lane >> 5) * 8 + r;
    wkA[idx] = f2bf(wk[(size_t)g * 16384 + o * 128 + d]);
    return;
  }
  idx -= 32768;
  if (idx < 131072) {
    int r = idx & 7, lane = (idx >> 3) & 63, ks = (idx >> 9) & 15, ot = (idx >> 13) & 7, g = idx >> 16;
    int o = ot * 32 + (lane & 31), q = ks * 16 + (lane >> 5) * 8 + r;
    w1A[idx] = f2bf(d2p_w1[(size_t)g * 65536 + o * 256 + q]);
    return;
  }
  idx -= 131072;
  if (idx < 65536) {
    int r = idx & 7, lane = (idx >> 3) & 63, ks = (idx >> 9) & 15, ot = (idx >> 13) & 3, g = idx >> 15;
    int o = ot * 32 + (lane & 31), q = ks * 16 + (lane >> 5) * 8 + r;
    w2A[idx] = f2bf(d2p_w2[(size_t)g * 32768 + o * 256 + q]);
    return;
  }
}

// ---------------- point-sim (r11 structure) + fused prep blocks ----------------
// grid = 1216: blocks [0,1152) do point-sim; blocks [1152,1216) do vp->bf16 + q/k proj.
__global__ __launch_bounds__(256, 2)
void k_point_sim(const float* __restrict__ vp,
                 const u16* __restrict__ w1p, const u16* __restrict__ w2p,
                 const float* __restrict__ g1v, const float* __restrict__ b1v,
                 const float* __restrict__ g2v, const float* __restrict__ b2v,
                 const float* __restrict__ w3v, const float* __restrict__ b3v,
                 float* __restrict__ s_out, float* __restrict__ sims_out,
                 const u16* __restrict__ wqA, const u16* __restrict__ wkA,
                 u16* __restrict__ Qb, u16* __restrict__ Kb,
                 u16* __restrict__ VPb, u16* __restrict__ VPT)
{
  const int orig = blockIdx.x;
  const int t = threadIdx.x;
  const int lane = t & 63;
  const int w = t >> 6;
  const int p_l = lane & 31;
  const int hi = lane >> 5;
  const float rsbn = rsqrtf(1.0f + 1e-5f);

  __shared__ u16 Adiff[2][32 * 128];     // 16 KB (prep branch reuses first 8 KB)
  __shared__ u16 HL[2][32 * 256];        // 32 KB
  __shared__ float sc1[256], bb1[256];
  __shared__ float sc2[128], bb2[128], w3s[128];
  __shared__ float sred[2][4][32];
  __shared__ float simv[128], svv[128];

  if (orig >= 1152) {
    // ================= PREP: vp -> bf16 (row + transposed) + q/k proj =================
    u16* VPs = (u16*)Adiff;   // [32][128] bf16 swizzled (8 KB)
    const int pb = orig - 1152;
    const int b = pb >> 2, nt = pb & 3;
    const int l31 = p_l;
    const float* vpb = vp + (size_t)b * 16384 + (size_t)nt * 32 * 128;
    {
      int r = t >> 3, cseg = t & 7;
      float v[16];
      const float4* src = (const float4*)(vpb + r * 128 + cseg * 16);
      #pragma unroll
      for (int c = 0; c < 4; ++c) {
        float4 a = src[c];
        v[c * 4 + 0] = a.x; v[c * 4 + 1] = a.y; v[c * 4 + 2] = a.z; v[c * 4 + 3] = a.w;
      }
      uint4 pk0, pk1;
      u32* p0 = (u32*)&pk0; u32* p1 = (u32*)&pk1;
      #pragma unroll
      for (int k = 0; k < 4; ++k) {
        p0[k] = cvtpk(v[k * 2 + 0], v[k * 2 + 1]);
        p1[k] = cvtpk(v[8 + k * 2 + 0], v[8 + k * 2 + 1]);
      }
      u16* vb = VPb + (size_t)b * 16384 + (nt * 32 + r) * 128 + cseg * 16;
      *(uint4*)(vb) = pk0;
      *(uint4*)(vb + 8) = pk1;
      *(uint4*)((char*)VPs + r * 256 + ((cseg * 32) ^ ((r & 15) << 4))) = pk0;
      *(uint4*)((char*)VPs + r * 256 + ((cseg * 32 + 16) ^ ((r & 15) << 4))) = pk1;
    }
    __syncthreads();
    {
      int col = t >> 1, hh = t & 1;
      u16 tmp[16];
      #pragma unroll
      for (int rr2 = 0; rr2 < 16; ++rr2) {
        int row = hh * 16 + rr2;
        tmp[rr2] = *(const u16*)((char*)VPs + row * 256 + ((col * 2) ^ ((row & 15) << 4)));
      }
      *(uint4*)(VPT + (size_t)b * 16384 + col * 128 + nt * 32 + hh * 16) = *(uint4*)&tmp[0];
      *(uint4*)(VPT + (size_t)b * 16384 + col * 128 + nt * 32 + hh * 16 + 8) = *(uint4*)&tmp[8];
    }
    {
      const int isK = w >> 1;
      const int otp = (w & 1) * 2;
      const u16* wA = isK ? wkA : wqA;
      u16* DST = (isK ? Kb : Qb) + (size_t)b * 16384;
      bh8 bf[8];
      #pragma unroll
      for (int ks = 0; ks < 8; ++ks)
        bf[ks] = *(const bh8*)((char*)VPs + l31 * 256 + (((ks * 32) + hi * 16) ^ ((l31 & 15) << 4)));
      #pragma unroll
      for (int oo = 0; oo < 2; ++oo) {
        int ot = otp + oo;
        f32x16 acc = zero16();
        #pragma unroll
        for (int ks = 0; ks < 8; ++ks) {
          bh8 af = *(const bh8*)(wA + ((size_t)(ot * 8 + ks) * 64 + lane) * 8);
          acc = __builtin_amdgcn_mfma_f32_32x32x16_bf16(af, bf[ks], acc, 0, 0, 0);
        }
        int n = nt * 32 + l31;
        #pragma unroll
        for (int q4 = 0; q4 < 4; ++q4) {
          int o0 = ot * 32 + q4 * 8 + hi * 4;
          uint2 pk;
          pk.x = cvtpk(acc[q4 * 4 + 0], acc[q4 * 4 + 1]);
          pk.y = cvtpk(acc[q4 * 4 + 2], acc[q4 * 4 + 3]);
          *(uint2*)(DST + n * 128 + o0) = pk;
        }
      }
    }
    return;
  }

  // ================= POINT-SIM (r11, proven) =================
  const int bid = (orig & 7) * 144 + (orig >> 3);   // bijective XCD swizzle
  const int half = bid & 1;
  int rem = (bid >> 1) % 36;
  const int b = (bid >> 1) / 36;
  int ti = 0;
  while (rem >= 8 - ti) { rem -= 8 - ti; ++ti; }
  const int tj = ti + rem;

  sc1[t] = g1v[t] * rsbn; bb1[t] = b1v[t];
  if (t < 128) { sc2[t] = g2v[t] * rsbn; bb2[t] = b2v[t]; w3s[t] = w3v[t]; }

  bh8 a1[2][8];
  #pragma unroll
  for (int c2 = 0; c2 < 2; ++c2)
    #pragma unroll
    for (int ks = 0; ks < 8; ++ks)
      a1[c2][ks] = *(const bh8*)(w1p + (((w * 2 + c2) * 8 + ks) * 64 + lane) * 8);
  bh8 a2[16];
  #pragma unroll
  for (int ks = 0; ks < 16; ++ks)
    a2[ks] = *(const bh8*)(w2p + ((w * 16 + ks) * 64 + lane) * 8);

  const int mtA = half * 4;
  const float* vpb = vp + (size_t)b * NN * DD;

  auto diffgen = [&](int mt, int buf) {
    int p = t >> 3, dseg = t & 7;
    int il = mt * 2 + (p >> 4), jl = p & 15;
    int i = ti * 16 + il, j = tj * 16 + jl;
    const float4* vi = (const float4*)(vpb + i * DD + dseg * 16);
    const float4* vj = (const float4*)(vpb + j * DD + dseg * 16);
    float rs = 0.f;
    u32 pw[8];
    #pragma unroll
    for (int c = 0; c < 4; ++c) {
      float4 av = vi[c], bv = vj[c];
      float d0 = av.x - bv.x; d0 *= d0;
      float d1 = av.y - bv.y; d1 *= d1;
      float d2 = av.z - bv.z; d2 *= d2;
      float d3 = av.w - bv.w; d3 *= d3;
      rs += d0 + d1 + d2 + d3;
      pw[c * 2]     = cvtpk(d0, d1);
      pw[c * 2 + 1] = cvtpk(d2, d3);
    }
    int base = p * 256;
    int off0 = (dseg * 32) ^ ((p & 15) << 4);
    int off1 = (dseg * 32 + 16) ^ ((p & 15) << 4);
    uint4 q0; q0.x = pw[0]; q0.y = pw[1]; q0.z = pw[2]; q0.w = pw[3];
    uint4 q1; q1.x = pw[4]; q1.y = pw[5]; q1.z = pw[6]; q1.w = pw[7];
    *(uint4*)((char*)Adiff[buf] + base + off0) = q0;
    *(uint4*)((char*)Adiff[buf] + base + off1) = q1;
    rs += __shfl_xor(rs, 1);
    rs += __shfl_xor(rs, 2);
    rs += __shfl_xor(rs, 4);
    if ((t & 7) == 0) simv[(mt - mtA) * 32 + p] = rs;
  };

  auto do_l2 = [&](int src) {
    f32x16 acc2 = zero16();
    __builtin_amdgcn_s_setprio(1);
    #pragma unroll
    for (int ks2 = 0; ks2 < 16; ++ks2) {
      int byte = p_l * 512 + ((ks2 * 32 + hi * 16) ^ (p_l << 4));
      bh8 bf = *(const bh8*)((const char*)HL[src] + byte);
      acc2 = __builtin_amdgcn_mfma_f32_32x32x16_bf16(a2[ks2], bf, acc2, 0, 0, 0);
    }
    __builtin_amdgcn_s_setprio(0);
    float psum = 0.f;
    #pragma unroll
    for (int r = 0; r < 16; ++r) {
      int e = w * 32 + (r & 3) + 8 * (r >> 2) + 4 * hi;
      float v = lrelu(acc2[r] * sc2[e] + bb2[e]);
      psum += v * w3s[e];
    }
    psum += __shfl_xor(psum, 32);
    if (hi == 0) sred[src][w][p_l] = psum;
  };

  auto s_final = [&](int ml) {
    if (t < 32) {
      float z = sred[ml & 1][0][t] + sred[ml & 1][1][t] + sred[ml & 1][2][t]
              + sred[ml & 1][3][t] + b3v[0];
      svv[ml * 32 + t] = 1.f / (1.f + __expf(-z));
    }
  };

  diffgen(mtA, 0);
  __syncthreads();

  #pragma unroll
  for (int m = 0; m < 4; ++m) {
    const int cur = m & 1;
    f32x16 acc1[2];
    acc1[0] = zero16(); acc1[1] = zero16();
    __builtin_amdgcn_s_setprio(1);
    #pragma unroll
    for (int ks = 0; ks < 8; ++ks) {
      int byte = p_l * 256 + ((ks * 32 + hi * 16) ^ ((p_l & 15) << 4));
      bh8 bf = *(const bh8*)((const char*)Adiff[cur] + byte);
      acc1[0] = __builtin_amdgcn_mfma_f32_32x32x16_bf16(a1[0][ks], bf, acc1[0], 0, 0, 0);
      acc1[1] = __builtin_amdgcn_mfma_f32_32x32x16_bf16(a1[1][ks], bf, acc1[1], 0, 0, 0);
    }
    __builtin_amdgcn_s_setprio(0);
    if (m < 3) diffgen(mtA + m + 1, cur ^ 1);
    if (m > 0) do_l2(cur ^ 1);
    if (m >= 2) s_final(m - 2);
    #pragma unroll
    for (int c2 = 0; c2 < 2; ++c2) {
      #pragma unroll
      for (int g4 = 0; g4 < 4; ++g4) {
        int c0 = (w * 2 + c2) * 32 + g4 * 8 + hi * 4;
        float v0 = lrelu(acc1[c2][g4 * 4 + 0] * sc1[c0 + 0] + bb1[c0 + 0]);
        float v1 = lrelu(acc1[c2][g4 * 4 + 1] * sc1[c0 + 1] + bb1[c0 + 1]);
        float v2 = lrelu(acc1[c2][g4 * 4 + 2] * sc1[c0 + 2] + bb1[c0 + 2]);
        float v3 = lrelu(acc1[c2][g4 * 4 + 3] * sc1[c0 + 3] + bb1[c0 + 3]);
        uint2 pk;
        pk.x = cvtpk(v0, v1);
        pk.y = cvtpk(v2, v3);
        int byte = p_l * 512 + ((c0 * 2) ^ (p_l << 4));
        *(uint2*)((char*)HL[cur] + byte) = pk;
      }
    }
    __syncthreads();
  }
  do_l2(1);
  s_final(2);
  __syncthreads();
  s_final(3);
  __syncthreads();

  {
    int idx = t & 127;
    int mm = idx >> 5, pp = idx & 31;
    int mt = mtA + mm;
    int i = ti * 16 + mt * 2 + (pp >> 4);
    int j = tj * 16 + (pp & 15);
    float sv = svv[idx];
    float sm = -simv[idx];
    if (t < 128) {
      s_out[(size_t)(b * NN + i) * NN + j] = sv;
      sims_out[(size_t)(b * NN + i) * NN + j] = sm;
    } else if (ti != tj) {
      s_out[(size_t)(b * NN + j) * NN + i] = sv;
      sims_out[(size_t)(b * NN + j) * NN + i] = sm;
    }
  }
}

// ---------------- top-k rank scatter ----------------
__global__ void k_rank(const float* __restrict__ s_buf, const float* __restrict__ ep_prev,
                       float* __restrict__ mask)
{
  const int b = blockIdx.x >> 7, n = blockIdx.x & 127, t = threadIdx.x;
  __shared__ float ev[NN];
  size_t row = (size_t)(b * NN + n) * NN;
  float v = s_buf[row + t] * ((t == n) ? 0.f : ep_prev[row + t]);
  ev[t] = v;
  __syncthreads();
  int r = 0;
  for (int j = 0; j < NN; ++j) {
    float vj = ev[j];
    r += (vj > v) || (vj == v && j < t);
  }
  if (r < 115) mask[(size_t)(b * NN + t) * NN + r] = 1.0f;
}

// ---------------- edge normalization (2 rows per block) ----------------
__global__ __launch_bounds__(256)
void k_edge(const float* __restrict__ s_buf, const float* __restrict__ ep_prev,
            float* __restrict__ maskb, int use_mask, float* __restrict__ eps_out)
{
  __shared__ float red[8];
  __shared__ float red2[4];
  const int t = threadIdx.x;
  const int rr = t >> 7, tl = t & 127;
  const int rowid = blockIdx.x * 2 + rr;
  const int i = rowid & 127;
  const int wl = (t >> 6) & 1;
  size_t row = (size_t)rowid * 128;
  float ep0 = (tl == i) ? 0.f : ep_prev[row + tl];
  float e = s_buf[row + tl] * ep0;
  if (use_mask) e *= maskb[row + tl];
  else maskb[row + tl] = 0.f;
  float a = ep0, c = fabsf(e);
  #pragma unroll
  for (int o = 32; o; o >>= 1) { a += __shfl_xor(a, o); c += __shfl_xor(c, o); }
  if ((t & 63) == 0) { red[(rr * 2 + wl) * 2 + 0] = a; red[(rr * 2 + wl) * 2 + 1] = c; }
  __syncthreads();
  float epsum = red[(rr * 2) * 2] + red[(rr * 2 + 1) * 2];
  float l1 = red[(rr * 2) * 2 + 1] + red[(rr * 2 + 1) * 2 + 1];
  e = e / fmaxf(l1, 1e-12f) * epsum;
  e += ((tl == i) ? 1.f : 0.f) + 1e-6f;
  float d = e;
  #pragma unroll
  for (int o = 32; o; o >>= 1) d += __shfl_xor(d, o);
  if ((t & 63) == 0) red2[rr * 2 + wl] = d;
  __syncthreads();
  eps_out[row + tl] = e / (red2[rr * 2] + red2[rr * 2 + 1]);
}

// ---------------- fused attn + fuse + l1 + aggr + MLP1 + MLP2 ----------------
__global__ __launch_bounds__(256)
void k_attn_d2p(const u16* __restrict__ Qb, const u16* __restrict__ Kb,
                const float* __restrict__ eps_g,
                const u16* __restrict__ VPb, const u16* __restrict__ VPT,
                const u16* __restrict__ w1A, const float* __restrict__ g1v, const float* __restrict__ b1v,
                const u16* __restrict__ w2A, const float* __restrict__ g2v, const float* __restrict__ b2v,
                float* __restrict__ vpn)
{
  __shared__ char shm[40960];
  u16* att  = (u16*)shm;             // 32 KB (dead after phase B)
  u16* AG   = (u16*)shm;             // 8 KB  aggr
  u16* HB   = (u16*)(shm + 8192);    // 16 KB h1
  u16* EFNl = (u16*)(shm + 32768);   // 8 KB

  const int b = blockIdx.x >> 2;
  const int ch = blockIdx.x & 3;
  const int t = threadIdx.x;
  const int w = t >> 6;
  const int lane = t & 63;
  const int l31 = lane & 31;
  const int hi = lane >> 5;
  const float rsbn = rsqrtf(1.f + 1e-5f);

  // ---- A: per-head logits + in-lane softmax + 2-head partial sum ----
  {
    float asum[64];
    #pragma unroll
    for (int z = 0; z < 64; ++z) asum[z] = 0.f;
    const u16* Qrow = Qb + (size_t)b * 16384 + (ch * 32 + l31) * 128;
    #pragma unroll
    for (int hh = 0; hh < 2; ++hh) {
      int h = w * 2 + hh;
      bh8 qf = *(const bh8*)(Qrow + h * 16 + hi * 8);
      f32x16 lg[4];
      #pragma unroll
      for (int jt = 0; jt < 4; ++jt) {
        bh8 kf = *(const bh8*)(Kb + (size_t)b * 16384 + (jt * 32 + l31) * 128 + h * 16 + hi * 8);
        f32x16 zz = zero16();
        lg[jt] = __builtin_amdgcn_mfma_f32_32x32x16_bf16(kf, qf, zz, 0, 0, 0);
      }
      float m = lg[0][0];
      #pragma unroll
      for (int jt = 0; jt < 4; ++jt)
        #pragma unroll
        for (int r = 0; r < 16; ++r) m = fmaxf(m, lg[jt][r]);
      m = fmaxf(m, __shfl_xor(m, 32));
      float sum = 0.f;
      #pragma unroll
      for (int jt = 0; jt < 4; ++jt)
        #pragma unroll
        for (int r = 0; r < 16; ++r) {
          float e = __expf((lg[jt][r] - m) * 0.25f);
          lg[jt][r] = e;
          sum += e;
        }
      sum += __shfl_xor(sum, 32);
      float inv = 1.f / sum;
      #pragma unroll
      for (int jt = 0; jt < 4; ++jt)
        #pragma unroll
        for (int r = 0; r < 16; ++r) asum[jt * 16 + r] += lg[jt][r] * inv;
    }
    #pragma unroll
    for (int jt = 0; jt < 4; ++jt)
      #pragma unroll
      for (int q4 = 0; q4 < 4; ++q4) {
        int j0 = jt * 32 + q4 * 8 + hi * 4;
        uint2 pk;
        pk.x = cvtpk(asum[jt * 16 + q4 * 4 + 0], asum[jt * 16 + q4 * 4 + 1]);
        pk.y = cvtpk(asum[jt * 16 + q4 * 4 + 2], asum[jt * 16 + q4 * 4 + 3]);
        *(uint2*)((char*)att + (w * 32 + l31) * 256 + ((j0 * 2) ^ ((l31 & 15) << 4))) = pk;
      }
  }
  __syncthreads();

  // ---- B: combine partials, fuse with eps, l1-normalize -> EFNl ----
  {
    int il = t >> 3, jseg = t & 7;
    int i = ch * 32 + il;
    float a[16];
    #pragma unroll
    for (int z = 0; z < 16; ++z) a[z] = 0.f;
    #pragma unroll
    for (int ww = 0; ww < 4; ++ww) {
      #pragma unroll
      for (int c = 0; c < 2; ++c) {
        uint4 v = *(const uint4*)((char*)att + (ww * 32 + il) * 256 + (((jseg * 32) + c * 16) ^ ((il & 15) << 4)));
        u32 uu[4] = {v.x, v.y, v.z, v.w};
        #pragma unroll
        for (int k = 0; k < 4; ++k) {
          a[c * 8 + k * 2 + 0] += bf2f((u16)(uu[k] & 0xffff));
          a[c * 8 + k * 2 + 1] += bf2f((u16)(uu[k] >> 16));
        }
      }
    }
    const float* erow = eps_g + ((size_t)b * 128 + i) * 128 + jseg * 16;
    float f[16];
    float s = 0.f;
    #pragma unroll
    for (int c = 0; c < 4; ++c) {
      float4 ev = *(const float4*)(erow + c * 4);
      float evs[4] = {ev.x, ev.y, ev.z, ev.w};
      #pragma unroll
      for (int k = 0; k < 4; ++k) {
        int jj = jseg * 16 + c * 4 + k;
        float fv = 0.5f * (evs[k] + a[c * 4 + k] * 0.125f);
        if (jj == i) fv = 0.f;
        f[c * 4 + k] = fv;
        s += fabsf(fv);
      }
    }
    s += __shfl_xor(s, 1);
    s += __shfl_xor(s, 2);
    s += __shfl_xor(s, 4);
    float inv = 1.f / fmaxf(s, 1e-12f);
    uint4 o0, o1;
    u32* op = (u32*)&o0;
    u32* op1 = (u32*)&o1;
    #pragma unroll
    for (int k = 0; k < 4; ++k) {
      op[k]  = cvtpk(f[k * 2 + 0] * inv, f[k * 2 + 1] * inv);
      op1[k] = cvtpk(f[8 + k * 2 + 0] * inv, f[8 + k * 2 + 1] * inv);
    }
    __syncthreads();
    *(uint4*)((char*)EFNl + il * 256 + ((jseg * 32) ^ ((il & 15) << 4))) = o0;
    *(uint4*)((char*)EFNl + il * 256 + ((jseg * 32 + 16) ^ ((il & 15) << 4))) = o1;
  }
  __syncthreads();

  // ---- C: aggr C[d][i] = sum_j vpT[d][j] * efn[i][j] ----
  {
    const u16* vtrow = VPT + (size_t)b * 16384 + (w * 32 + l31) * 128;
    f32x16 acc = zero16();
    #pragma unroll
    for (int ks = 0; ks < 8; ++ks) {
      bh8 af = *(const bh8*)(vtrow + ks * 16 + hi * 8);
      bh8 bf = *(const bh8*)((char*)EFNl + l31 * 256 + (((ks * 32) + hi * 16) ^ ((l31 & 15) << 4)));
      acc = __builtin_amdgcn_mfma_f32_32x32x16_bf16(af, bf, acc, 0, 0, 0);
    }
    #pragma unroll
    for (int q4 = 0; q4 < 4; ++q4) {
      int d0 = w * 32 + q4 * 8 + hi * 4;
      uint2 pk;
      pk.x = cvtpk(acc[q4 * 4 + 0], acc[q4 * 4 + 1]);
      pk.y = cvtpk(acc[q4 * 4 + 2], acc[q4 * 4 + 3]);
      *(uint2*)((char*)AG + l31 * 256 + ((d0 * 2) ^ ((l31 & 15) << 4))) = pk;
    }
  }
  __syncthreads();

  // ---- D: MLP1 ----
  {
    const u16* vprow = VPb + (size_t)b * 16384 + (ch * 32 + l31) * 128;
    f32x16 acc0 = zero16(), acc1v = zero16();
    #pragma unroll
    for (int ks = 0; ks < 16; ++ks) {
      bh8 a0 = *(const bh8*)(w1A + ((size_t)((w * 2 + 0) * 16 + ks)) * 512 + lane * 8);
      bh8 a1 = *(const bh8*)(w1A + ((size_t)((w * 2 + 1) * 16 + ks)) * 512 + lane * 8);
      bh8 bf;
      if (ks < 8) bf = *(const bh8*)(vprow + ks * 16 + hi * 8);
      else bf = *(const bh8*)((char*)AG + l31 * 256 + ((((ks - 8) * 32) + hi * 16) ^ ((l31 & 15) << 4)));
      acc0 = __builtin_amdgcn_mfma_f32_32x32x16_bf16(a0, bf, acc0, 0, 0, 0);
      acc1v = __builtin_amdgcn_mfma_f32_32x32x16_bf16(a1, bf, acc1v, 0, 0, 0);
    }
    #pragma unroll
    for (int oo = 0; oo < 2; ++oo) {
      const f32x16& acc = oo ? acc1v : acc0;
      #pragma unroll
      for (int q4 = 0; q4 < 4; ++q4) {
        int o0 = (w * 2 + oo) * 32 + q4 * 8 + hi * 4;
        float4 gg = *(const float4*)(g1v + o0);
        float4 bb = *(const float4*)(b1v + o0);
        float v0 = lrelu(acc[q4 * 4 + 0] * (gg.x * rsbn) + bb.x);
        float v1 = lrelu(acc[q4 * 4 + 1] * (gg.y * rsbn) + bb.y);
        float v2 = lrelu(acc[q4 * 4 + 2] * (gg.z * rsbn) + bb.z);
        float v3 = lrelu(acc[q4 * 4 + 3] * (gg.w * rsbn) + bb.w);
        uint2 pk;
        pk.x = cvtpk(v0, v1);
        pk.y = cvtpk(v2, v3);
        *(uint2*)((char*)HB + l31 * 512 + ((o0 * 2) ^ (l31 << 4))) = pk;
      }
    }
  }
  __syncthreads();

  // ---- E: MLP2 -> vpn ----
  {
    f32x16 acc = zero16();
    #pragma unroll
    for (int ks = 0; ks < 16; ++ks) {
      bh8 af = *(const bh8*)(w2A + ((size_t)(w * 16 + ks)) * 512 + lane * 8);
      bh8 bf = *(const bh8*)((char*)HB + l31 * 512 + (((ks * 32) + hi * 16) ^ (l31 << 4)));
      acc = __builtin_amdgcn_mfma_f32_32x32x16_bf16(af, bf, acc, 0, 0, 0);
    }
    int i = ch * 32 + l31;
    #pragma unroll
    for (int q4 = 0; q4 < 4; ++q4) {
      int o0 = w * 32 + q4 * 8 + hi * 4;
      float4 gg = *(const float4*)(g2v + o0);
      float4 bb = *(const float4*)(b2v + o0);
      float4 ov;
      ov.x = lrelu(acc[q4 * 4 + 0] * (gg.x * rsbn) + bb.x);
      ov.y = lrelu(acc[q4 * 4 + 1] * (gg.y * rsbn) + bb.y);
      ov.z = lrelu(acc[q4 * 4 + 2] * (gg.z * rsbn) + bb.z);
      ov.w = lrelu(acc[q4 * 4 + 3] * (gg.w * rsbn) + bb.w);
      *(float4*)(vpn + ((size_t)b * 128 + i) * 128 + o0) = ov;
    }
  }
}

extern "C" void kernel_launch(void* const* d_in, const int* in_sizes, int n_in,
                              void* d_out, int out_size, void* d_ws, size_t ws_size,
                              hipStream_t stream)
{
  (void)in_sizes; (void)n_in; (void)out_size; (void)ws_size;
  const float* vp_in  = (const float*)d_in[0];
  const float* ep_in  = (const float*)d_in[1];
  const float* ps_w1  = (const float*)d_in[2];
  const float* ps_g1  = (const float*)d_in[3];
  const float* ps_b1  = (const float*)d_in[4];
  const float* ps_w2  = (const float*)d_in[5];
  const float* ps_g2  = (const float*)d_in[6];
  const float* ps_b2  = (const float*)d_in[7];
  const float* ps_w3  = (const float*)d_in[8];
  const float* ps_b3  = (const float*)d_in[9];
  const float* d2p_w1 = (const float*)d_in[10];
  const float* d2p_g1 = (const float*)d_in[11];
  const float* d2p_b1 = (const float*)d_in[12];
  const float* d2p_w2 = (const float*)d_in[13];
  const float* d2p_g2 = (const float*)d_in[14];
  const float* d2p_b2 = (const float*)d_in[15];
  const float* wq     = (const float*)d_in[16];
  const float* wk     = (const float*)d_in[17];

  float* out = (float*)d_out;
  float* eps_base  = out;                 // [2][16][128][128]
  float* sims_base = out + 524288;        // [2][16][128][128]
  float* vp_out    = out + 1048576;       // [16][128][128]

  char* ws = (char*)d_ws;
  float* s_buf = (float*)(ws + ((size_t)0 << 20));
  float* maskb = (float*)(ws + ((size_t)1 << 20));
  float* vp1   = (float*)(ws + ((size_t)2 << 20));
  u16* Qb   = (u16*)(ws + ((size_t)3 << 20));
  u16* Kb   = (u16*)(ws + ((size_t)3 << 20) + 524288);
  u16* VPb  = (u16*)(ws + ((size_t)4 << 20));
  u16* VPT  = (u16*)(ws + ((size_t)4 << 20) + 524288);
  u16* w1p  = (u16*)(ws + ((size_t)5 << 20));
  u16* w2p  = w1p + 65536;
  u16* wqA  = w2p + 65536;      // [g][4][8][512]
  u16* wkA  = wqA + 32768;
  u16* w1A  = wkA + 32768;      // [g][8][16][512]
  u16* w2A  = w1A + 131072;     // [g][4][16][512]

  k_pack<<<dim3(1536), 256, 0, stream>>>(ps_w1, ps_w2, d2p_w1, d2p_w2, wq, wk,
                                         w1p, w2p, wqA, wkA, w1A, w2A);

  for (int g = 0; g < 2; ++g) {
    const float* vpc = g ? (const float*)vp1 : vp_in;
    float* vpn = g ? vp_out : vp1;
    float* eps_g  = eps_base + (size_t)g * 262144;
    float* sims_g = sims_base + (size_t)g * 262144;
    const float* epprev = g ? eps_base : ep_in;

    k_point_sim<<<dim3(1216), 256, 0, stream>>>(vpc,
        w1p + (size_t)g * 32768, w2p + (size_t)g * 32768,
        ps_g1 + g * 256, ps_b1 + g * 256,
        ps_g2 + g * 128, ps_b2 + g * 128,
        ps_w3 + g * 128, ps_b3 + g, s_buf, sims_g,
        wqA + (size_t)g * 16384, wkA + (size_t)g * 16384, Qb, Kb, VPb, VPT);
    if (g) k_rank<<<dim3(2048), 128, 0, stream>>>(s_buf, epprev, maskb);
    k_edge<<<dim3(1024), 256, 0, stream>>>(s_buf, epprev, maskb, g, eps_g);
    k_attn_d2p<<<dim3(64), 256, 0, stream>>>(Qb, Kb, eps_g, VPb, VPT,
        w1A + (size_t)g * 65536, d2p_g1 + g * 256, d2p_b1 + g * 256,
        w2A + (size_t)g * 32768, d2p_g2 + g * 128, d2p_b2 + g * 128, vpn);
  }
}

// Round 15
// 110.712 us; speedup vs baseline: 2.3436x; 1.0534x over previous
//
#include <hip/hip_runtime.h>
#include <hip/hip_bf16.h>

typedef unsigned int u32;
typedef unsigned short u16;
typedef float f32x4 __attribute__((ext_vector_type(4)));
typedef float f32x16 __attribute__((ext_vector_type(16)));
typedef short bh8 __attribute__((ext_vector_type(8)));   // 8 bf16 operand frag

#define NB 16
#define NN 128
#define DD 128

__device__ __forceinline__ u16 f2bf(float f) {
  union { float f; u32 u; } x; x.f = f;
  u32 r = (x.u + 0x7fffu + ((x.u >> 16) & 1u)) >> 16;
  return (u16)r;
}
__device__ __forceinline__ u32 cvtpk(float lo, float hi) {
  u32 r;
  asm("v_cvt_pk_bf16_f32 %0, %1, %2" : "=v"(r) : "v"(lo), "v"(hi));
  return r;
}
__device__ __forceinline__ float bf2f(u16 h) {
  union { u32 u; float f; } x; x.u = ((u32)h) << 16;
  return x.f;
}
__device__ __forceinline__ float lrelu(float x) { return fmaxf(x, 0.01f * x); }
__device__ __forceinline__ f32x16 zero16() {
  f32x16 v;
  #pragma unroll
  for (int r = 0; r < 16; ++r) v[r] = 0.f;
  return v;
}

// ---------------- unified weight pack/convert ----------------
__global__ void k_pack(const float* __restrict__ ps_w1, const float* __restrict__ ps_w2,
                       const float* __restrict__ d2p_w1, const float* __restrict__ d2p_w2,
                       const float* __restrict__ wq, const float* __restrict__ wk,
                       u16* __restrict__ w1p, u16* __restrict__ w2p,
                       u16* __restrict__ wqA, u16* __restrict__ wkA,
                       u16* __restrict__ w1A, u16* __restrict__ w2A)
{
  int idx = blockIdx.x * 256 + threadIdx.x;
  if (idx < 65536) {
    int r = idx & 7, lane = (idx >> 3) & 63, f = (idx >> 9) & 63, g = idx >> 15;
    int ct = f >> 3, ks = f & 7;
    int c = ct * 32 + (lane & 31), d = ks * 16 + (lane >> 5) * 8 + r;
    w1p[idx] = f2bf(ps_w1[(size_t)g * 32768 + c * 128 + d]);
    return;
  }
  idx -= 65536;
  if (idx < 65536) {
    int r = idx & 7, lane = (idx >> 3) & 63, f = (idx >> 9) & 63, g = idx >> 15;
    int et = f >> 4, ks2 = f & 15;
    int e = et * 32 + (lane & 31), c = ks2 * 16 + (lane >> 5) * 8 + r;
    w2p[idx] = f2bf(ps_w2[(size_t)g * 32768 + e * 256 + c]);
    return;
  }
  idx -= 65536;
  if (idx < 32768) {
    int r = idx & 7, lane = (idx >> 3) & 63, ks = (idx >> 9) & 7, ot = (idx >> 12) & 3, g = idx >> 14;
    int o = ot * 32 + (lane & 31), d = ks * 16 + (lane >> 5) * 8 + r;
    wqA[idx] = f2bf(wq[(size_t)g * 16384 + o * 128 + d]);
    return;
  }
  idx -= 32768;
  if (idx < 32768) {
    int r = idx & 7, lane = (idx >> 3) & 63, ks = (idx >> 9) & 7, ot = (idx >> 12) & 3, g = idx >> 14;
    int o = ot * 32 + (lane & 31), d = ks * 16 + (lane >> 5) * 8 + r;
    wkA[idx] = f2bf(wk[(size_t)g * 16384 + o * 128 + d]);
    return;
  }
  idx -= 32768;
  if (idx < 131072) {
    int r = idx & 7, lane = (idx >> 3) & 63, ks = (idx >> 9) & 15, ot = (idx >> 13) & 7, g = idx >> 16;
    int o = ot * 32 + (lane & 31), q = ks * 16 + (lane >> 5) * 8 + r;
    w1A[idx] = f2bf(d2p_w1[(size_t)g * 65536 + o * 256 + q]);
    return;
  }
  idx -= 131072;
  if (idx < 65536) {
    int r = idx & 7, lane = (idx >> 3) & 63, ks = (idx >> 9) & 15, ot = (idx >> 13) & 3, g = idx >> 15;
    int o = ot * 32 + (lane & 31), q = ks * 16 + (lane >> 5) * 8 + r;
    w2A[idx] = f2bf(d2p_w2[(size_t)g * 32768 + o * 256 + q]);
    return;
  }
}

// ---------------- point-sim (r11 structure) + fused prep blocks ----------------
// grid = 1216: blocks [0,1152) do point-sim; blocks [1152,1216) do vp->bf16 + q/k proj.
__global__ __launch_bounds__(256, 2)
void k_point_sim(const float* __restrict__ vp,
                 const u16* __restrict__ w1p, const u16* __restrict__ w2p,
                 const float* __restrict__ g1v, const float* __restrict__ b1v,
                 const float* __restrict__ g2v, const float* __restrict__ b2v,
                 const float* __restrict__ w3v, const float* __restrict__ b3v,
                 float* __restrict__ s_out, float* __restrict__ sims_out,
                 const u16* __restrict__ wqA, const u16* __restrict__ wkA,
                 u16* __restrict__ Qb, u16* __restrict__ Kb,
                 u16* __restrict__ VPb, u16* __restrict__ VPT)
{
  const int orig = blockIdx.x;
  const int t = threadIdx.x;
  const int lane = t & 63;
  const int w = t >> 6;
  const int p_l = lane & 31;
  const int hi = lane >> 5;
  const float rsbn = rsqrtf(1.0f + 1e-5f);

  __shared__ u16 Adiff[2][32 * 128];     // 16 KB (prep branch reuses first 8 KB)
  __shared__ u16 HL[2][32 * 256];        // 32 KB
  __shared__ float sc1[256], bb1[256];
  __shared__ float sc2[128], bb2[128], w3s[128];
  __shared__ float sred[2][4][32];
  __shared__ float simv[128], svv[128];

  if (orig >= 1152) {
    // ================= PREP: vp -> bf16 (row + transposed) + q/k proj =================
    u16* VPs = (u16*)Adiff;   // [32][128] bf16 swizzled (8 KB)
    const int pb = orig - 1152;
    const int b = pb >> 2, nt = pb & 3;
    const int l31 = p_l;
    const float* vpb = vp + (size_t)b * 16384 + (size_t)nt * 32 * 128;
    {
      int r = t >> 3, cseg = t & 7;
      float v[16];
      const float4* src = (const float4*)(vpb + r * 128 + cseg * 16);
      #pragma unroll
      for (int c = 0; c < 4; ++c) {
        float4 a = src[c];
        v[c * 4 + 0] = a.x; v[c * 4 + 1] = a.y; v[c * 4 + 2] = a.z; v[c * 4 + 3] = a.w;
      }
      uint4 pk0, pk1;
      u32* p0 = (u32*)&pk0; u32* p1 = (u32*)&pk1;
      #pragma unroll
      for (int k = 0; k < 4; ++k) {
        p0[k] = cvtpk(v[k * 2 + 0], v[k * 2 + 1]);
        p1[k] = cvtpk(v[8 + k * 2 + 0], v[8 + k * 2 + 1]);
      }
      u16* vb = VPb + (size_t)b * 16384 + (nt * 32 + r) * 128 + cseg * 16;
      *(uint4*)(vb) = pk0;
      *(uint4*)(vb + 8) = pk1;
      *(uint4*)((char*)VPs + r * 256 + ((cseg * 32) ^ ((r & 15) << 4))) = pk0;
      *(uint4*)((char*)VPs + r * 256 + ((cseg * 32 + 16) ^ ((r & 15) << 4))) = pk1;
    }
    __syncthreads();
    {
      int col = t >> 1, hh = t & 1;
      u16 tmp[16];
      #pragma unroll
      for (int rr2 = 0; rr2 < 16; ++rr2) {
        int row = hh * 16 + rr2;
        tmp[rr2] = *(const u16*)((char*)VPs + row * 256 + ((col * 2) ^ ((row & 15) << 4)));
      }
      *(uint4*)(VPT + (size_t)b * 16384 + col * 128 + nt * 32 + hh * 16) = *(uint4*)&tmp[0];
      *(uint4*)(VPT + (size_t)b * 16384 + col * 128 + nt * 32 + hh * 16 + 8) = *(uint4*)&tmp[8];
    }
    {
      const int isK = w >> 1;
      const int otp = (w & 1) * 2;
      const u16* wA = isK ? wkA : wqA;
      u16* DST = (isK ? Kb : Qb) + (size_t)b * 16384;
      bh8 bf[8];
      #pragma unroll
      for (int ks = 0; ks < 8; ++ks)
        bf[ks] = *(const bh8*)((char*)VPs + l31 * 256 + (((ks * 32) + hi * 16) ^ ((l31 & 15) << 4)));
      #pragma unroll
      for (int oo = 0; oo < 2; ++oo) {
        int ot = otp + oo;
        f32x16 acc = zero16();
        #pragma unroll
        for (int ks = 0; ks < 8; ++ks) {
          bh8 af = *(const bh8*)(wA + ((size_t)(ot * 8 + ks) * 64 + lane) * 8);
          acc = __builtin_amdgcn_mfma_f32_32x32x16_bf16(af, bf[ks], acc, 0, 0, 0);
        }
        int n = nt * 32 + l31;
        #pragma unroll
        for (int q4 = 0; q4 < 4; ++q4) {
          int o0 = ot * 32 + q4 * 8 + hi * 4;
          uint2 pk;
          pk.x = cvtpk(acc[q4 * 4 + 0], acc[q4 * 4 + 1]);
          pk.y = cvtpk(acc[q4 * 4 + 2], acc[q4 * 4 + 3]);
          *(uint2*)(DST + n * 128 + o0) = pk;
        }
      }
    }
    return;
  }

  // ================= POINT-SIM =================
  const int bid = (orig & 7) * 144 + (orig >> 3);   // bijective XCD swizzle
  const int half = bid & 1;
  int rem = (bid >> 1) % 36;
  const int b = (bid >> 1) / 36;
  int ti = 0;
  while (rem >= 8 - ti) { rem -= 8 - ti; ++ti; }
  const int tj = ti + rem;

  sc1[t] = g1v[t] * rsbn; bb1[t] = b1v[t];
  if (t < 128) { sc2[t] = g2v[t] * rsbn; bb2[t] = b2v[t]; w3s[t] = w3v[t]; }

  bh8 a1[2][8];
  #pragma unroll
  for (int c2 = 0; c2 < 2; ++c2)
    #pragma unroll
    for (int ks = 0; ks < 8; ++ks)
      a1[c2][ks] = *(const bh8*)(w1p + (((w * 2 + c2) * 8 + ks) * 64 + lane) * 8);
  bh8 a2[16];
  #pragma unroll
  for (int ks = 0; ks < 16; ++ks)
    a2[ks] = *(const bh8*)(w2p + ((w * 16 + ks) * 64 + lane) * 8);

  const int mtA = half * 4;
  const float* vpb = vp + (size_t)b * NN * DD;

  auto diffgen = [&](int mt, int buf) {
    int p = t >> 3, dseg = t & 7;
    int il = mt * 2 + (p >> 4), jl = p & 15;
    int i = ti * 16 + il, j = tj * 16 + jl;
    const float4* vi = (const float4*)(vpb + i * DD + dseg * 16);
    const float4* vj = (const float4*)(vpb + j * DD + dseg * 16);
    float rs = 0.f;
    u32 pw[8];
    #pragma unroll
    for (int c = 0; c < 4; ++c) {
      float4 av = vi[c], bv = vj[c];
      float d0 = av.x - bv.x; d0 *= d0;
      float d1 = av.y - bv.y; d1 *= d1;
      float d2 = av.z - bv.z; d2 *= d2;
      float d3 = av.w - bv.w; d3 *= d3;
      rs += d0 + d1 + d2 + d3;
      pw[c * 2]     = cvtpk(d0, d1);
      pw[c * 2 + 1] = cvtpk(d2, d3);
    }
    int base = p * 256;
    int off0 = (dseg * 32) ^ ((p & 15) << 4);
    int off1 = (dseg * 32 + 16) ^ ((p & 15) << 4);
    uint4 q0; q0.x = pw[0]; q0.y = pw[1]; q0.z = pw[2]; q0.w = pw[3];
    uint4 q1; q1.x = pw[4]; q1.y = pw[5]; q1.z = pw[6]; q1.w = pw[7];
    *(uint4*)((char*)Adiff[buf] + base + off0) = q0;
    *(uint4*)((char*)Adiff[buf] + base + off1) = q1;
    rs += __shfl_xor(rs, 1);
    rs += __shfl_xor(rs, 2);
    rs += __shfl_xor(rs, 4);
    if ((t & 7) == 0) simv[(mt - mtA) * 32 + p] = rs;
  };

  auto do_l2 = [&](int src) {
    f32x16 acc2 = zero16();
    __builtin_amdgcn_s_setprio(1);
    #pragma unroll
    for (int ks2 = 0; ks2 < 16; ++ks2) {
      int byte = p_l * 512 + ((ks2 * 32 + hi * 16) ^ (p_l << 4));
      bh8 bf = *(const bh8*)((const char*)HL[src] + byte);
      acc2 = __builtin_amdgcn_mfma_f32_32x32x16_bf16(a2[ks2], bf, acc2, 0, 0, 0);
    }
    __builtin_amdgcn_s_setprio(0);
    float psum = 0.f;
    #pragma unroll
    for (int r = 0; r < 16; ++r) {
      int e = w * 32 + (r & 3) + 8 * (r >> 2) + 4 * hi;
      float v = lrelu(acc2[r] * sc2[e] + bb2[e]);
      psum += v * w3s[e];
    }
    psum += __shfl_xor(psum, 32);
    if (hi == 0) sred[src][w][p_l] = psum;
  };

  auto s_final = [&](int ml) {
    if (t < 32) {
      float z = sred[ml & 1][0][t] + sred[ml & 1][1][t] + sred[ml & 1][2][t]
              + sred[ml & 1][3][t] + b3v[0];
      svv[ml * 32 + t] = 1.f / (1.f + __expf(-z));
    }
  };

  diffgen(mtA, 0);
  __syncthreads();

  #pragma unroll
  for (int m = 0; m < 4; ++m) {
    const int cur = m & 1;
    f32x16 acc1[2];
    acc1[0] = zero16(); acc1[1] = zero16();
    __builtin_amdgcn_s_setprio(1);
    #pragma unroll
    for (int ks = 0; ks < 8; ++ks) {
      int byte = p_l * 256 + ((ks * 32 + hi * 16) ^ ((p_l & 15) << 4));
      bh8 bf = *(const bh8*)((const char*)Adiff[cur] + byte);
      acc1[0] = __builtin_amdgcn_mfma_f32_32x32x16_bf16(a1[0][ks], bf, acc1[0], 0, 0, 0);
      acc1[1] = __builtin_amdgcn_mfma_f32_32x32x16_bf16(a1[1][ks], bf, acc1[1], 0, 0, 0);
    }
    __builtin_amdgcn_s_setprio(0);
    if (m < 3) diffgen(mtA + m + 1, cur ^ 1);
    if (m > 0) do_l2(cur ^ 1);
    if (m >= 2) s_final(m - 2);
    #pragma unroll
    for (int c2 = 0; c2 < 2; ++c2) {
      #pragma unroll
      for (int g4 = 0; g4 < 4; ++g4) {
        int c0 = (w * 2 + c2) * 32 + g4 * 8 + hi * 4;
        float v0 = lrelu(acc1[c2][g4 * 4 + 0] * sc1[c0 + 0] + bb1[c0 + 0]);
        float v1 = lrelu(acc1[c2][g4 * 4 + 1] * sc1[c0 + 1] + bb1[c0 + 1]);
        float v2 = lrelu(acc1[c2][g4 * 4 + 2] * sc1[c0 + 2] + bb1[c0 + 2]);
        float v3 = lrelu(acc1[c2][g4 * 4 + 3] * sc1[c0 + 3] + bb1[c0 + 3]);
        uint2 pk;
        pk.x = cvtpk(v0, v1);
        pk.y = cvtpk(v2, v3);
        int byte = p_l * 512 + ((c0 * 2) ^ (p_l << 4));
        *(uint2*)((char*)HL[cur] + byte) = pk;
      }
    }
    __syncthreads();
  }
  do_l2(1);
  s_final(2);
  __syncthreads();
  s_final(3);
  __syncthreads();

  {
    int idx = t & 127;
    int mm = idx >> 5, pp = idx & 31;
    int mt = mtA + mm;
    int i = ti * 16 + mt * 2 + (pp >> 4);
    int j = tj * 16 + (pp & 15);
    float sv = svv[idx];
    float sm = -simv[idx];
    if (t < 128) {
      s_out[(size_t)(b * NN + i) * NN + j] = sv;
      sims_out[(size_t)(b * NN + i) * NN + j] = sm;
    } else if (ti != tj) {
      s_out[(size_t)(b * NN + j) * NN + i] = sv;
      sims_out[(size_t)(b * NN + j) * NN + i] = sm;
    }
  }
}

// ---------------- top-k rank scatter ----------------
__global__ void k_rank(const float* __restrict__ s_buf, const float* __restrict__ ep_prev,
                       float* __restrict__ mask)
{
  const int b = blockIdx.x >> 7, n = blockIdx.x & 127, t = threadIdx.x;
  __shared__ float ev[NN];
  size_t row = (size_t)(b * NN + n) * NN;
  float v = s_buf[row + t] * ((t == n) ? 0.f : ep_prev[row + t]);
  ev[t] = v;
  __syncthreads();
  int r = 0;
  for (int j = 0; j < NN; ++j) {
    float vj = ev[j];
    r += (vj > v) || (vj == v && j < t);
  }
  if (r < 115) mask[(size_t)(b * NN + t) * NN + r] = 1.0f;
}

// ---------------- fused edge + attn + fuse + l1 + aggr + MLP1 + MLP2 ----------------
// prologue computes this block's 32 eps rows (register-resident), writes eps_g, and
// (g=0) zeroes maskb; 64 blocks cover all 2048 rows.
__global__ __launch_bounds__(256)
void k_attn_d2p(const u16* __restrict__ Qb, const u16* __restrict__ Kb,
                const float* __restrict__ s_buf, const float* __restrict__ ep_prev,
                float* __restrict__ maskb, int use_mask, float* __restrict__ eps_g,
                const u16* __restrict__ VPb, const u16* __restrict__ VPT,
                const u16* __restrict__ w1A, const float* __restrict__ g1v, const float* __restrict__ b1v,
                const u16* __restrict__ w2A, const float* __restrict__ g2v, const float* __restrict__ b2v,
                float* __restrict__ vpn)
{
  __shared__ char shm[40960];
  u16* att  = (u16*)shm;             // 32 KB (dead after phase B)
  u16* AG   = (u16*)shm;             // 8 KB  aggr
  u16* HB   = (u16*)(shm + 8192);    // 16 KB h1
  u16* EFNl = (u16*)(shm + 32768);   // 8 KB

  const int b = blockIdx.x >> 2;
  const int ch = blockIdx.x & 3;
  const int t = threadIdx.x;
  const int w = t >> 6;
  const int lane = t & 63;
  const int l31 = lane & 31;
  const int hi = lane >> 5;
  const float rsbn = rsqrtf(1.f + 1e-5f);

  // ---- P0: edge normalization for this block's 32 rows (register-resident) ----
  float epsv[16];
  {
    const int il = t >> 3, jseg = t & 7;
    const int i = ch * 32 + il;
    size_t row = ((size_t)b * 128 + i) * 128;
    float ep0s = 0.f, l1s = 0.f;
    float ee[16];
    #pragma unroll
    for (int c = 0; c < 4; ++c) {
      float4 sv = *(const float4*)(s_buf + row + jseg * 16 + c * 4);
      float4 pv = *(const float4*)(ep_prev + row + jseg * 16 + c * 4);
      float svs[4] = {sv.x, sv.y, sv.z, sv.w};
      float pvs[4] = {pv.x, pv.y, pv.z, pv.w};
      #pragma unroll
      for (int k = 0; k < 4; ++k) {
        int j = jseg * 16 + c * 4 + k;
        float p0 = (j == i) ? 0.f : pvs[k];
        ep0s += p0;
        ee[c * 4 + k] = svs[k] * p0;
      }
    }
    if (use_mask) {
      #pragma unroll
      for (int c = 0; c < 4; ++c) {
        float4 mv = *(const float4*)(maskb + row + jseg * 16 + c * 4);
        float ms[4] = {mv.x, mv.y, mv.z, mv.w};
        #pragma unroll
        for (int k = 0; k < 4; ++k) ee[c * 4 + k] *= ms[k];
      }
    } else {
      float4 zz; zz.x = 0.f; zz.y = 0.f; zz.z = 0.f; zz.w = 0.f;
      #pragma unroll
      for (int c = 0; c < 4; ++c)
        *(float4*)(maskb + row + jseg * 16 + c * 4) = zz;
    }
    #pragma unroll
    for (int k = 0; k < 16; ++k) l1s += fabsf(ee[k]);
    ep0s += __shfl_xor(ep0s, 1); ep0s += __shfl_xor(ep0s, 2); ep0s += __shfl_xor(ep0s, 4);
    l1s  += __shfl_xor(l1s, 1);  l1s  += __shfl_xor(l1s, 2);  l1s  += __shfl_xor(l1s, 4);
    float scale = ep0s / fmaxf(l1s, 1e-12f);
    float d = 0.f;
    #pragma unroll
    for (int k = 0; k < 16; ++k) {
      int j = jseg * 16 + k;
      float v = ee[k] * scale + ((j == i) ? 1.f : 0.f) + 1e-6f;
      ee[k] = v;
      d += v;
    }
    d += __shfl_xor(d, 1); d += __shfl_xor(d, 2); d += __shfl_xor(d, 4);
    float invd = 1.f / d;
    #pragma unroll
    for (int k = 0; k < 16; ++k) epsv[k] = ee[k] * invd;
    #pragma unroll
    for (int c = 0; c < 4; ++c) {
      float4 ov;
      ov.x = epsv[c * 4 + 0]; ov.y = epsv[c * 4 + 1];
      ov.z = epsv[c * 4 + 2]; ov.w = epsv[c * 4 + 3];
      *(float4*)(eps_g + row + jseg * 16 + c * 4) = ov;
    }
  }

  // ---- A: per-head logits + in-lane softmax + 2-head partial sum ----
  {
    float asum[64];
    #pragma unroll
    for (int z = 0; z < 64; ++z) asum[z] = 0.f;
    const u16* Qrow = Qb + (size_t)b * 16384 + (ch * 32 + l31) * 128;
    #pragma unroll
    for (int hh = 0; hh < 2; ++hh) {
      int h = w * 2 + hh;
      bh8 qf = *(const bh8*)(Qrow + h * 16 + hi * 8);
      f32x16 lg[4];
      #pragma unroll
      for (int jt = 0; jt < 4; ++jt) {
        bh8 kf = *(const bh8*)(Kb + (size_t)b * 16384 + (jt * 32 + l31) * 128 + h * 16 + hi * 8);
        f32x16 zz = zero16();
        lg[jt] = __builtin_amdgcn_mfma_f32_32x32x16_bf16(kf, qf, zz, 0, 0, 0);
      }
      float m = lg[0][0];
      #pragma unroll
      for (int jt = 0; jt < 4; ++jt)
        #pragma unroll
        for (int r = 0; r < 16; ++r) m = fmaxf(m, lg[jt][r]);
      m = fmaxf(m, __shfl_xor(m, 32));
      float sum = 0.f;
      #pragma unroll
      for (int jt = 0; jt < 4; ++jt)
        #pragma unroll
        for (int r = 0; r < 16; ++r) {
          float e = __expf((lg[jt][r] - m) * 0.25f);
          lg[jt][r] = e;
          sum += e;
        }
      sum += __shfl_xor(sum, 32);
      float inv = 1.f / sum;
      #pragma unroll
      for (int jt = 0; jt < 4; ++jt)
        #pragma unroll
        for (int r = 0; r < 16; ++r) asum[jt * 16 + r] += lg[jt][r] * inv;
    }
    #pragma unroll
    for (int jt = 0; jt < 4; ++jt)
      #pragma unroll
      for (int q4 = 0; q4 < 4; ++q4) {
        int j0 = jt * 32 + q4 * 8 + hi * 4;
        uint2 pk;
        pk.x = cvtpk(asum[jt * 16 + q4 * 4 + 0], asum[jt * 16 + q4 * 4 + 1]);
        pk.y = cvtpk(asum[jt * 16 + q4 * 4 + 2], asum[jt * 16 + q4 * 4 + 3]);
        *(uint2*)((char*)att + (w * 32 + l31) * 256 + ((j0 * 2) ^ ((l31 & 15) << 4))) = pk;
      }
  }
  __syncthreads();

  // ---- B: combine partials, fuse with eps (regs), l1-normalize -> EFNl ----
  {
    int il = t >> 3, jseg = t & 7;
    int i = ch * 32 + il;
    float a[16];
    #pragma unroll
    for (int z = 0; z < 16; ++z) a[z] = 0.f;
    #pragma unroll
    for (int ww = 0; ww < 4; ++ww) {
      #pragma unroll
      for (int c = 0; c < 2; ++c) {
        uint4 v = *(const uint4*)((char*)att + (ww * 32 + il) * 256 + (((jseg * 32) + c * 16) ^ ((il & 15) << 4)));
        u32 uu[4] = {v.x, v.y, v.z, v.w};
        #pragma unroll
        for (int k = 0; k < 4; ++k) {
          a[c * 8 + k * 2 + 0] += bf2f((u16)(uu[k] & 0xffff));
          a[c * 8 + k * 2 + 1] += bf2f((u16)(uu[k] >> 16));
        }
      }
    }
    float f[16];
    float s = 0.f;
    #pragma unroll
    for (int c = 0; c < 4; ++c) {
      #pragma unroll
      for (int k = 0; k < 4; ++k) {
        int jj = jseg * 16 + c * 4 + k;
        float fv = 0.5f * (epsv[c * 4 + k] + a[c * 4 + k] * 0.125f);
        if (jj == i) fv = 0.f;
        f[c * 4 + k] = fv;
        s += fabsf(fv);
      }
    }
    s += __shfl_xor(s, 1);
    s += __shfl_xor(s, 2);
    s += __shfl_xor(s, 4);
    float inv = 1.f / fmaxf(s, 1e-12f);
    uint4 o0, o1;
    u32* op = (u32*)&o0;
    u32* op1 = (u32*)&o1;
    #pragma unroll
    for (int k = 0; k < 4; ++k) {
      op[k]  = cvtpk(f[k * 2 + 0] * inv, f[k * 2 + 1] * inv);
      op1[k] = cvtpk(f[8 + k * 2 + 0] * inv, f[8 + k * 2 + 1] * inv);
    }
    __syncthreads();
    *(uint4*)((char*)EFNl + il * 256 + ((jseg * 32) ^ ((il & 15) << 4))) = o0;
    *(uint4*)((char*)EFNl + il * 256 + ((jseg * 32 + 16) ^ ((il & 15) << 4))) = o1;
  }
  __syncthreads();

  // ---- C: aggr C[d][i] = sum_j vpT[d][j] * efn[i][j] ----
  {
    const u16* vtrow = VPT + (size_t)b * 16384 + (w * 32 + l31) * 128;
    f32x16 acc = zero16();
    #pragma unroll
    for (int ks = 0; ks < 8; ++ks) {
      bh8 af = *(const bh8*)(vtrow + ks * 16 + hi * 8);
      bh8 bf = *(const bh8*)((char*)EFNl + l31 * 256 + (((ks * 32) + hi * 16) ^ ((l31 & 15) << 4)));
      acc = __builtin_amdgcn_mfma_f32_32x32x16_bf16(af, bf, acc, 0, 0, 0);
    }
    #pragma unroll
    for (int q4 = 0; q4 < 4; ++q4) {
      int d0 = w * 32 + q4 * 8 + hi * 4;
      uint2 pk;
      pk.x = cvtpk(acc[q4 * 4 + 0], acc[q4 * 4 + 1]);
      pk.y = cvtpk(acc[q4 * 4 + 2], acc[q4 * 4 + 3]);
      *(uint2*)((char*)AG + l31 * 256 + ((d0 * 2) ^ ((l31 & 15) << 4))) = pk;
    }
  }
  __syncthreads();

  // ---- D: MLP1 ----
  {
    const u16* vprow = VPb + (size_t)b * 16384 + (ch * 32 + l31) * 128;
    f32x16 acc0 = zero16(), acc1v = zero16();
    #pragma unroll
    for (int ks = 0; ks < 16; ++ks) {
      bh8 a0 = *(const bh8*)(w1A + ((size_t)((w * 2 + 0) * 16 + ks)) * 512 + lane * 8);
      bh8 a1 = *(const bh8*)(w1A + ((size_t)((w * 2 + 1) * 16 + ks)) * 512 + lane * 8);
      bh8 bf;
      if (ks < 8) bf = *(const bh8*)(vprow + ks * 16 + hi * 8);
      else bf = *(const bh8*)((char*)AG + l31 * 256 + ((((ks - 8) * 32) + hi * 16) ^ ((l31 & 15) << 4)));
      acc0 = __builtin_amdgcn_mfma_f32_32x32x16_bf16(a0, bf, acc0, 0, 0, 0);
      acc1v = __builtin_amdgcn_mfma_f32_32x32x16_bf16(a1, bf, acc1v, 0, 0, 0);
    }
    #pragma unroll
    for (int oo = 0; oo < 2; ++oo) {
      const f32x16& acc = oo ? acc1v : acc0;
      #pragma unroll
      for (int q4 = 0; q4 < 4; ++q4) {
        int o0 = (w * 2 + oo) * 32 + q4 * 8 + hi * 4;
        float4 gg = *(const float4*)(g1v + o0);
        float4 bb = *(const float4*)(b1v + o0);
        float v0 = lrelu(acc[q4 * 4 + 0] * (gg.x * rsbn) + bb.x);
        float v1 = lrelu(acc[q4 * 4 + 1] * (gg.y * rsbn) + bb.y);
        float v2 = lrelu(acc[q4 * 4 + 2] * (gg.z * rsbn) + bb.z);
        float v3 = lrelu(acc[q4 * 4 + 3] * (gg.w * rsbn) + bb.w);
        uint2 pk;
        pk.x = cvtpk(v0, v1);
        pk.y = cvtpk(v2, v3);
        *(uint2*)((char*)HB + l31 * 512 + ((o0 * 2) ^ (l31 << 4))) = pk;
      }
    }
  }
  __syncthreads();

  // ---- E: MLP2 -> vpn ----
  {
    f32x16 acc = zero16();
    #pragma unroll
    for (int ks = 0; ks < 16; ++ks) {
      bh8 af = *(const bh8*)(w2A + ((size_t)(w * 16 + ks)) * 512 + lane * 8);
      bh8 bf = *(const bh8*)((char*)HB + l31 * 512 + (((ks * 32) + hi * 16) ^ (l31 << 4)));
      acc = __builtin_amdgcn_mfma_f32_32x32x16_bf16(af, bf, acc, 0, 0, 0);
    }
    int i = ch * 32 + l31;
    #pragma unroll
    for (int q4 = 0; q4 < 4; ++q4) {
      int o0 = w * 32 + q4 * 8 + hi * 4;
      float4 gg = *(const float4*)(g2v + o0);
      float4 bb = *(const float4*)(b2v + o0);
      float4 ov;
      ov.x = lrelu(acc[q4 * 4 + 0] * (gg.x * rsbn) + bb.x);
      ov.y = lrelu(acc[q4 * 4 + 1] * (gg.y * rsbn) + bb.y);
      ov.z = lrelu(acc[q4 * 4 + 2] * (gg.z * rsbn) + bb.z);
      ov.w = lrelu(acc[q4 * 4 + 3] * (gg.w * rsbn) + bb.w);
      *(float4*)(vpn + ((size_t)b * 128 + i) * 128 + o0) = ov;
    }
  }
}

extern "C" void kernel_launch(void* const* d_in, const int* in_sizes, int n_in,
                              void* d_out, int out_size, void* d_ws, size_t ws_size,
                              hipStream_t stream)
{
  (void)in_sizes; (void)n_in; (void)out_size; (void)ws_size;
  const float* vp_in  = (const float*)d_in[0];
  const float* ep_in  = (const float*)d_in[1];
  const float* ps_w1  = (const float*)d_in[2];
  const float* ps_g1  = (const float*)d_in[3];
  const float* ps_b1  = (const float*)d_in[4];
  const float* ps_w2  = (const float*)d_in[5];
  const float* ps_g2  = (const float*)d_in[6];
  const float* ps_b2  = (const float*)d_in[7];
  const float* ps_w3  = (const float*)d_in[8];
  const float* ps_b3  = (const float*)d_in[9];
  const float* d2p_w1 = (const float*)d_in[10];
  const float* d2p_g1 = (const float*)d_in[11];
  const float* d2p_b1 = (const float*)d_in[12];
  const float* d2p_w2 = (const float*)d_in[13];
  const float* d2p_g2 = (const float*)d_in[14];
  const float* d2p_b2 = (const float*)d_in[15];
  const float* wq     = (const float*)d_in[16];
  const float* wk     = (const float*)d_in[17];

  float* out = (float*)d_out;
  float* eps_base  = out;                 // [2][16][128][128]
  float* sims_base = out + 524288;        // [2][16][128][128]
  float* vp_out    = out + 1048576;       // [16][128][128]

  char* ws = (char*)d_ws;
  float* s_buf = (float*)(ws + ((size_t)0 << 20));
  float* maskb = (float*)(ws + ((size_t)1 << 20));
  float* vp1   = (float*)(ws + ((size_t)2 << 20));
  u16* Qb   = (u16*)(ws + ((size_t)3 << 20));
  u16* Kb   = (u16*)(ws + ((size_t)3 << 20) + 524288);
  u16* VPb  = (u16*)(ws + ((size_t)4 << 20));
  u16* VPT  = (u16*)(ws + ((size_t)4 << 20) + 524288);
  u16* w1p  = (u16*)(ws + ((size_t)5 << 20));
  u16* w2p  = w1p + 65536;
  u16* wqA  = w2p + 65536;      // [g][4][8][512]
  u16* wkA  = wqA + 32768;
  u16* w1A  = wkA + 32768;      // [g][8][16][512]
  u16* w2A  = w1A + 131072;     // [g][4][16][512]

  k_pack<<<dim3(1536), 256, 0, stream>>>(ps_w1, ps_w2, d2p_w1, d2p_w2, wq, wk,
                                         w1p, w2p, wqA, wkA, w1A, w2A);

  for (int g = 0; g < 2; ++g) {
    const float* vpc = g ? (const float*)vp1 : vp_in;
    float* vpn = g ? vp_out : vp1;
    float* eps_g  = eps_base + (size_t)g * 262144;
    float* sims_g = sims_base + (size_t)g * 262144;
    const float* epprev = g ? eps_base : ep_in;

    k_point_sim<<<dim3(1216), 256, 0, stream>>>(vpc,
        w1p + (size_t)g * 32768, w2p + (size_t)g * 32768,
        ps_g1 + g * 256, ps_b1 + g * 256,
        ps_g2 + g * 128, ps_b2 + g * 128,
        ps_w3 + g * 128, ps_b3 + g, s_buf, sims_g,
        wqA + (size_t)g * 16384, wkA + (size_t)g * 16384, Qb, Kb, VPb, VPT);
    if (g) k_rank<<<dim3(2048), 128, 0, stream>>>(s_buf, epprev, maskb);
    k_attn_d2p<<<dim3(64), 256, 0, stream>>>(Qb, Kb,
        s_buf, epprev, maskb, g, eps_g, VPb, VPT,
        w1A + (size_t)g * 65536, d2p_g1 + g * 256, d2p_b1 + g * 256,
        w2A + (size_t)g * 32768, d2p_g2 + g * 128, d2p_b2 + g * 128, vpn);
  }
}